// Round 1
// baseline (4285.435 us; speedup 1.0000x reference)
//
#include <hip/hip_runtime.h>
#include <math.h>

#define N_PTS 100000
#define KDIM 128
#define CDIM 128          // IN_C == OUT_C == 128
#define TILE_N 64
#define NB1 ((N_PTS + TILE_N - 1) / TILE_N)   // 1563 C1 blocks

// ---------------- Kernel A: spec partials: partials[b][k][i] = sum over block-b's n-chunk of U[n,k]*x[n,i]
__global__ __launch_bounds__(256) void kA(const float* __restrict__ U,
                                          const float* __restrict__ x,
                                          float* __restrict__ partials,
                                          int chunk) {
    __shared__ float Us[32 * 128];
    __shared__ float Xs[32 * 128];
    const int tid = threadIdx.x;
    const int b = blockIdx.x;
    const int n_begin = b * chunk;
    const int n_end = min(N_PTS, n_begin + chunk);
    const int tk = tid >> 4;      // 0..15 -> k block
    const int ti = tid & 15;      // 0..15 -> i block
    float acc[8][8];
#pragma unroll
    for (int a = 0; a < 8; ++a)
#pragma unroll
        for (int c = 0; c < 8; ++c) acc[a][c] = 0.0f;

    for (int n0 = n_begin; n0 < n_end; n0 += 32) {
        // stage 32 rows of U and x (4096 floats each; 4 float4 per thread per array)
#pragma unroll
        for (int r = 0; r < 4; ++r) {
            int idx = (r * 256 + tid) * 4;   // [0,4096)
            int n = idx >> 7;
            int k = idx & 127;
            int gn = n0 + n;
            float4 u4 = make_float4(0, 0, 0, 0), x4 = make_float4(0, 0, 0, 0);
            if (gn < n_end) {
                u4 = *(const float4*)&U[(size_t)gn * 128 + k];
                x4 = *(const float4*)&x[(size_t)gn * 128 + k];
            }
            *(float4*)&Us[n * 128 + k] = u4;
            *(float4*)&Xs[n * 128 + k] = x4;
        }
        __syncthreads();
        int nn = min(32, n_end - n0);
        for (int n = 0; n < nn; ++n) {
            float4 ua = *(float4*)&Us[n * 128 + tk * 8];
            float4 ub = *(float4*)&Us[n * 128 + tk * 8 + 4];
            float4 xa = *(float4*)&Xs[n * 128 + ti * 8];
            float4 xb = *(float4*)&Xs[n * 128 + ti * 8 + 4];
            float u[8] = {ua.x, ua.y, ua.z, ua.w, ub.x, ub.y, ub.z, ub.w};
            float xv[8] = {xa.x, xa.y, xa.z, xa.w, xb.x, xb.y, xb.z, xb.w};
#pragma unroll
            for (int a = 0; a < 8; ++a)
#pragma unroll
                for (int c = 0; c < 8; ++c) acc[a][c] += u[a] * xv[c];
        }
        __syncthreads();
    }
    float* p = partials + (size_t)b * 16384;
#pragma unroll
    for (int a = 0; a < 8; ++a)
#pragma unroll
        for (int c = 0; c < 8; c += 4) {
            *(float4*)&p[(tk * 8 + a) * 128 + ti * 8 + c] =
                make_float4(acc[a][c], acc[a][c + 1], acc[a][c + 2], acc[a][c + 3]);
        }
}

// ---------------- Kernel A2: spec[j] = sum_b partials[b][j]
__global__ __launch_bounds__(256) void kA2(const float* __restrict__ partials,
                                           float* __restrict__ spec, int nA) {
    int j = blockIdx.x * 256 + threadIdx.x;   // grid 64 -> j in [0,16384)
    float s = 0.0f;
    for (int b = 0; b < nA; ++b) s += partials[(size_t)b * 16384 + j];
    spec[j] = s;
}

// ---------------- Kernel B: mixedT[k][o] = sum_i coeffs[o][k][i]*spec[k][i]; one wave per (o,k)
__global__ __launch_bounds__(256) void kB(const float* __restrict__ coeffs,
                                          const float* __restrict__ spec,
                                          float* __restrict__ mixedT) {
    int wave = (blockIdx.x * 256 + threadIdx.x) >> 6;   // [0, 16384)
    int lane = threadIdx.x & 63;
    int o = wave >> 7;
    int k = wave & 127;
    float2 c2 = *(const float2*)&coeffs[((size_t)o * 128 + k) * 128 + lane * 2];
    float2 s2 = *(const float2*)&spec[k * 128 + lane * 2];
    float v = c2.x * s2.x + c2.y * s2.y;
#pragma unroll
    for (int s = 32; s >= 1; s >>= 1) v += __shfl_xor(v, s);
    if (lane == 0) mixedT[k * 128 + o] = v;
}

// ---------------- Kernel C1: logits tile (64n x 128o), fused local softmax stats.
// Writes exp(logit - m_block) to out[n][o]; writes (m_block, l_block) partials.
__global__ __launch_bounds__(256) void kC1(const float* __restrict__ U,
                                           const float* __restrict__ mixedT,
                                           float* __restrict__ out,
                                           float* __restrict__ m_part,
                                           float* __restrict__ l_part) {
    __shared__ float Ut[128 * 68];    // [k][n], stride 68 (16B-aligned rows, low conflict)
    __shared__ float Mx[32 * 128];    // mixedT k-chunk [kk][o]
    __shared__ float red[16 * 129];   // [tn][o] reduction scratch
    const int tid = threadIdx.x;
    const int b = blockIdx.x;
    const int n0 = b * TILE_N;

    // stage U transposed: 64 n x 128 k
    for (int r = 0; r < 32; ++r) {
        int idx = r * 256 + tid;       // [0, 8192)
        int n = idx >> 7;
        int k = idx & 127;
        int gn = n0 + n;
        Ut[k * 68 + n] = (gn < N_PTS) ? U[(size_t)gn * 128 + k] : 0.0f;
    }

    const int tn = tid & 15;    // n sub-block (4 n each)
    const int to = tid >> 4;    // o sub-block (8 o each)
    float acc[4][8];
#pragma unroll
    for (int a = 0; a < 4; ++a)
#pragma unroll
        for (int c = 0; c < 8; ++c) acc[a][c] = 0.0f;

    for (int kc = 0; kc < 128; kc += 32) {
        __syncthreads();   // covers Ut staging (first iter) + Mx reuse (later iters)
#pragma unroll
        for (int r = 0; r < 4; ++r) {
            int idx = (r * 256 + tid) * 4;   // [0,4096)
            int kk = idx >> 7;
            int o = idx & 127;
            *(float4*)&Mx[kk * 128 + o] = *(const float4*)&mixedT[(kc + kk) * 128 + o];
        }
        __syncthreads();
        for (int k = 0; k < 32; ++k) {
            float4 u4 = *(float4*)&Ut[(kc + k) * 68 + tn * 4];
            float4 m0 = *(float4*)&Mx[k * 128 + to * 8];
            float4 m1 = *(float4*)&Mx[k * 128 + to * 8 + 4];
            float um[4] = {u4.x, u4.y, u4.z, u4.w};
            float mm[8] = {m0.x, m0.y, m0.z, m0.w, m1.x, m1.y, m1.z, m1.w};
#pragma unroll
            for (int a = 0; a < 4; ++a)
#pragma unroll
                for (int c = 0; c < 8; ++c) acc[a][c] += um[a] * mm[c];
        }
    }
    __syncthreads();

    const int n_base = n0 + tn * 4;
#pragma unroll
    for (int a = 0; a < 4; ++a)
        if (n_base + a >= N_PTS) {
#pragma unroll
            for (int c = 0; c < 8; ++c) acc[a][c] = -3.4e38f;
        }

    // ---- per-o max over the tile's 64 n
#pragma unroll
    for (int c = 0; c < 8; ++c) {
        float m = fmaxf(fmaxf(acc[0][c], acc[1][c]), fmaxf(acc[2][c], acc[3][c]));
        red[tn * 129 + to * 8 + c] = m;
    }
    __syncthreads();
    for (int s = 8; s >= 1; s >>= 1) {
        if (tn < s) {
#pragma unroll
            for (int c = 0; c < 8; ++c) {
                int o = to * 8 + c;
                red[tn * 129 + o] = fmaxf(red[tn * 129 + o], red[(tn + s) * 129 + o]);
            }
        }
        __syncthreads();
    }
    float mb[8];
#pragma unroll
    for (int c = 0; c < 8; ++c) mb[c] = red[to * 8 + c];
    float mval = (tid < 128) ? red[tid] : 0.0f;
    __syncthreads();

    // ---- exp, write unnormalized, local sums
    float sums[8];
#pragma unroll
    for (int c = 0; c < 8; ++c) sums[c] = 0.0f;
#pragma unroll
    for (int a = 0; a < 4; ++a) {
        float e[8];
#pragma unroll
        for (int c = 0; c < 8; ++c) {
            e[c] = __expf(acc[a][c] - mb[c]);
            sums[c] += e[c];
        }
        if (n_base + a < N_PTS) {
            *(float4*)&out[(size_t)(n_base + a) * 128 + to * 8] =
                make_float4(e[0], e[1], e[2], e[3]);
            *(float4*)&out[(size_t)(n_base + a) * 128 + to * 8 + 4] =
                make_float4(e[4], e[5], e[6], e[7]);
        }
    }
#pragma unroll
    for (int c = 0; c < 8; ++c) red[tn * 129 + to * 8 + c] = sums[c];
    __syncthreads();
    for (int s = 8; s >= 1; s >>= 1) {
        if (tn < s) {
#pragma unroll
            for (int c = 0; c < 8; ++c) {
                int o = to * 8 + c;
                red[tn * 129 + o] += red[(tn + s) * 129 + o];
            }
        }
        __syncthreads();
    }
    if (tid < 128) {
        m_part[(size_t)b * 128 + tid] = mval;
        l_part[(size_t)b * 128 + tid] = red[tid];
    }
}

// ---------------- Kernel C2: combine (m,l) over blocks; emit scale[o][b] = exp(m_b - m)/l
__global__ __launch_bounds__(256) void kC2(const float* __restrict__ m_part,
                                           const float* __restrict__ l_part,
                                           float* __restrict__ scale) {
    const int o = blockIdx.x;
    const int tid = threadIdx.x;
    __shared__ float sm[256];
    float m = -3.4e38f;
    for (int b = tid; b < NB1; b += 256) m = fmaxf(m, m_part[(size_t)b * 128 + o]);
    sm[tid] = m;
    __syncthreads();
    for (int s = 128; s >= 1; s >>= 1) {
        if (tid < s) sm[tid] = fmaxf(sm[tid], sm[tid + s]);
        __syncthreads();
    }
    m = sm[0];
    __syncthreads();
    float l = 0.0f;
    for (int b = tid; b < NB1; b += 256)
        l += l_part[(size_t)b * 128 + o] * __expf(m_part[(size_t)b * 128 + o] - m);
    sm[tid] = l;
    __syncthreads();
    for (int s = 128; s >= 1; s >>= 1) {
        if (tid < s) sm[tid] += sm[tid + s];
        __syncthreads();
    }
    l = sm[0];
    float inv = 1.0f / l;
    for (int b = tid; b < NB1; b += 256)
        scale[(size_t)o * NB1 + b] = __expf(m_part[(size_t)b * 128 + o] - m) * inv;
}

// ---------------- Kernel C3: out[n][o] *= scale[o][n/64]
__global__ __launch_bounds__(256) void kC3(float* __restrict__ out,
                                           const float* __restrict__ scale) {
    const int b = blockIdx.x;
    const int tid = threadIdx.x;
    __shared__ float sc[128];
    if (tid < 128) sc[tid] = scale[(size_t)tid * NB1 + b];
    __syncthreads();
    const int n0 = b * TILE_N;
#pragma unroll
    for (int r = 0; r < 8; ++r) {
        int idx = (r * 256 + tid) * 4;   // [0,8192)
        int n = idx >> 7;
        int o = idx & 127;
        int gn = n0 + n;
        if (gn < N_PTS) {
            float4 v = *(float4*)&out[(size_t)gn * 128 + o];
            v.x *= sc[o];
            v.y *= sc[o + 1];
            v.z *= sc[o + 2];
            v.w *= sc[o + 3];
            *(float4*)&out[(size_t)gn * 128 + o] = v;
        }
    }
}

extern "C" void kernel_launch(void* const* d_in, const int* in_sizes, int n_in,
                              void* d_out, int out_size, void* d_ws, size_t ws_size,
                              hipStream_t stream) {
    const float* x = (const float*)d_in[0];       // (N, 128)
    const float* U = (const float*)d_in[1];       // (N, 128)
    const float* coeffs = (const float*)d_in[2];  // (128, 128, 128)
    float* out = (float*)d_out;                   // (N, 128)

    // workspace layout (floats)
    float* f = (float*)d_ws;
    float* spec = f;                         // 16384
    float* mixedT = spec + 16384;            // 16384
    float* m_part = mixedT + 16384;          // NB1*128
    float* l_part = m_part + (size_t)NB1 * 128;
    float* scale = l_part + (size_t)NB1 * 128;   // 128*NB1
    float* partialsA = scale + (size_t)128 * NB1;

    size_t fixed_bytes = ((size_t)(16384 * 2) + (size_t)NB1 * 128 * 3) * 4;
    int nA = 512;
    if (ws_size > fixed_bytes) {
        size_t avail = (ws_size - fixed_bytes) / 65536;   // 64KB per partial
        if ((size_t)nA > avail) nA = (int)avail;
    } else {
        nA = 1;
    }
    if (nA < 1) nA = 1;
    int chunk = (N_PTS + nA - 1) / nA;

    kA<<<nA, 256, 0, stream>>>(U, x, partialsA, chunk);
    kA2<<<64, 256, 0, stream>>>(partialsA, spec, nA);
    kB<<<4096, 256, 0, stream>>>(coeffs, spec, mixedT);
    kC1<<<NB1, 256, 0, stream>>>(U, mixedT, out, m_part, l_part);
    kC2<<<128, 256, 0, stream>>>(m_part, l_part, scale);
    kC3<<<NB1, 256, 0, stream>>>(out, scale);
}

// Round 2
// 402.280 us; speedup vs baseline: 10.6529x; 10.6529x over previous
//
#include <hip/hip_runtime.h>
#include <math.h>

#define N_PTS 100000
#define KDIM 128
#define CDIM 128          // IN_C == OUT_C == 128
#define TILE_N 64
#define NB1 ((N_PTS + TILE_N - 1) / TILE_N)   // 1563 C1 blocks

// ---------------- Kernel A: spec partials: partials[b][k][i] = sum over block-b's n-chunk of U[n,k]*x[n,i]
__global__ __launch_bounds__(256) void kA(const float* __restrict__ U,
                                          const float* __restrict__ x,
                                          float* __restrict__ partials,
                                          int chunk) {
    __shared__ float Us[32 * 128];
    __shared__ float Xs[32 * 128];
    const int tid = threadIdx.x;
    const int b = blockIdx.x;
    const int n_begin = b * chunk;
    const int n_end = min(N_PTS, n_begin + chunk);
    const int tk = tid >> 4;      // 0..15 -> k block
    const int ti = tid & 15;      // 0..15 -> i block
    float acc[8][8];
#pragma unroll
    for (int a = 0; a < 8; ++a)
#pragma unroll
        for (int c = 0; c < 8; ++c) acc[a][c] = 0.0f;

    for (int n0 = n_begin; n0 < n_end; n0 += 32) {
#pragma unroll
        for (int r = 0; r < 4; ++r) {
            int idx = (r * 256 + tid) * 4;   // [0,4096)
            int n = idx >> 7;
            int k = idx & 127;
            int gn = n0 + n;
            float4 u4 = make_float4(0, 0, 0, 0), x4 = make_float4(0, 0, 0, 0);
            if (gn < n_end) {
                u4 = *(const float4*)&U[(size_t)gn * 128 + k];
                x4 = *(const float4*)&x[(size_t)gn * 128 + k];
            }
            *(float4*)&Us[n * 128 + k] = u4;
            *(float4*)&Xs[n * 128 + k] = x4;
        }
        __syncthreads();
        int nn = min(32, n_end - n0);
        for (int n = 0; n < nn; ++n) {
            float4 ua = *(float4*)&Us[n * 128 + tk * 8];
            float4 ub = *(float4*)&Us[n * 128 + tk * 8 + 4];
            float4 xa = *(float4*)&Xs[n * 128 + ti * 8];
            float4 xb = *(float4*)&Xs[n * 128 + ti * 8 + 4];
            float u[8] = {ua.x, ua.y, ua.z, ua.w, ub.x, ub.y, ub.z, ub.w};
            float xv[8] = {xa.x, xa.y, xa.z, xa.w, xb.x, xb.y, xb.z, xb.w};
#pragma unroll
            for (int a = 0; a < 8; ++a)
#pragma unroll
                for (int c = 0; c < 8; ++c) acc[a][c] += u[a] * xv[c];
        }
        __syncthreads();
    }
    float* p = partials + (size_t)b * 16384;
#pragma unroll
    for (int a = 0; a < 8; ++a)
#pragma unroll
        for (int c = 0; c < 8; c += 4) {
            *(float4*)&p[(tk * 8 + a) * 128 + ti * 8 + c] =
                make_float4(acc[a][c], acc[a][c + 1], acc[a][c + 2], acc[a][c + 3]);
        }
}

// ---------------- Kernel A2: spec[j] = sum_b partials[b][j]
__global__ __launch_bounds__(256) void kA2(const float* __restrict__ partials,
                                           float* __restrict__ spec, int nA) {
    int j = blockIdx.x * 256 + threadIdx.x;   // grid 64 -> j in [0,16384)
    float s = 0.0f;
    for (int b = 0; b < nA; ++b) s += partials[(size_t)b * 16384 + j];
    spec[j] = s;
}

// ---------------- Kernel B: mixedT[k][o] = sum_i coeffs[o][k][i]*spec[k][i]; one wave per (o,k)
__global__ __launch_bounds__(256) void kB(const float* __restrict__ coeffs,
                                          const float* __restrict__ spec,
                                          float* __restrict__ mixedT) {
    int wave = (blockIdx.x * 256 + threadIdx.x) >> 6;   // [0, 16384)
    int lane = threadIdx.x & 63;
    int o = wave >> 7;
    int k = wave & 127;
    float2 c2 = *(const float2*)&coeffs[((size_t)o * 128 + k) * 128 + lane * 2];
    float2 s2 = *(const float2*)&spec[k * 128 + lane * 2];
    float v = c2.x * s2.x + c2.y * s2.y;
#pragma unroll
    for (int s = 32; s >= 1; s >>= 1) v += __shfl_xor(v, s);
    if (lane == 0) mixedT[k * 128 + o] = v;
}

// ---------------- Kernel C1: logits tile (64n x 128o), fused local softmax stats.
// 512 threads; per-thread 2n x 8o (acc = 16 VGPR). Softmax stats via shfl
// butterfly over the 32 tn-lanes (each half-wave spans all 64 n). No LDS
// reduction scratch. Writes exp(logit - m_block) to out; (m,l) partials to ws.
__global__ __launch_bounds__(512) void kC1(const float* __restrict__ U,
                                           const float* __restrict__ mixedT,
                                           float* __restrict__ out,
                                           float* __restrict__ m_part,
                                           float* __restrict__ l_part) {
    __shared__ float Ut[128 * 66];    // [k][n], stride 66 (b64-read conflict-free, 8B aligned)
    __shared__ float Mx[32 * 128];    // mixedT k-chunk [kk][o]
    const int tid = threadIdx.x;
    const int b = blockIdx.x;
    const int n0 = b * TILE_N;
    const int tn = tid & 31;    // n pair index: rows 2*tn, 2*tn+1
    const int to = tid >> 5;    // o group: 8 o's at to*8

    // ---- stage U transposed: issue 4 float4 loads, then 16 scalar LDS writes
    float4 uv[4];
#pragma unroll
    for (int r = 0; r < 4; ++r) {
        int idx = (r * 512 + tid) * 4;   // [0,8192)
        int n = idx >> 7;
        int k = idx & 127;
        int gn = n0 + n;
        uv[r] = (gn < N_PTS) ? *(const float4*)&U[(size_t)gn * 128 + k]
                             : make_float4(0, 0, 0, 0);
    }
#pragma unroll
    for (int r = 0; r < 4; ++r) {
        int idx = (r * 512 + tid) * 4;
        int n = idx >> 7;
        int k = idx & 127;
        Ut[(k + 0) * 66 + n] = uv[r].x;
        Ut[(k + 1) * 66 + n] = uv[r].y;
        Ut[(k + 2) * 66 + n] = uv[r].z;
        Ut[(k + 3) * 66 + n] = uv[r].w;
    }

    float acc0[8], acc1[8];
#pragma unroll
    for (int c = 0; c < 8; ++c) { acc0[c] = 0.0f; acc1[c] = 0.0f; }

    for (int kc = 0; kc < 128; kc += 32) {
        __syncthreads();   // Ut staging done (first iter) / Mx no longer in use (later)
#pragma unroll
        for (int r = 0; r < 2; ++r) {
            int idx = (r * 512 + tid) * 4;   // [0,4096)
            int kk = idx >> 7;
            int o = idx & 127;
            *(float4*)&Mx[kk * 128 + o] = *(const float4*)&mixedT[(kc + kk) * 128 + o];
        }
        __syncthreads();
        for (int k = 0; k < 32; ++k) {
            float2 u2 = *(float2*)&Ut[(kc + k) * 66 + tn * 2];
            float4 m0 = *(float4*)&Mx[k * 128 + to * 8];
            float4 m1 = *(float4*)&Mx[k * 128 + to * 8 + 4];
            float mm[8] = {m0.x, m0.y, m0.z, m0.w, m1.x, m1.y, m1.z, m1.w};
#pragma unroll
            for (int c = 0; c < 8; ++c) {
                acc0[c] += u2.x * mm[c];
                acc1[c] += u2.y * mm[c];
            }
        }
    }

    // ---- tail guard
    const int gn0 = n0 + tn * 2;
    if (gn0 >= N_PTS) {
#pragma unroll
        for (int c = 0; c < 8; ++c) acc0[c] = -3.4e38f;
    }
    if (gn0 + 1 >= N_PTS) {
#pragma unroll
        for (int c = 0; c < 8; ++c) acc1[c] = -3.4e38f;
    }

    // ---- per-o tile max: butterfly over 32 tn-lanes (same half-wave, same to)
    float mb[8];
#pragma unroll
    for (int c = 0; c < 8; ++c) mb[c] = fmaxf(acc0[c], acc1[c]);
#pragma unroll
    for (int s = 1; s < 32; s <<= 1) {
#pragma unroll
        for (int c = 0; c < 8; ++c) mb[c] = fmaxf(mb[c], __shfl_xor(mb[c], s));
    }

    // ---- exp, write unnormalized, butterfly local sum
    float e0[8], e1[8], lsum[8];
#pragma unroll
    for (int c = 0; c < 8; ++c) {
        e0[c] = __expf(acc0[c] - mb[c]);
        e1[c] = __expf(acc1[c] - mb[c]);
        lsum[c] = e0[c] + e1[c];
    }
    if (gn0 < N_PTS) {
        *(float4*)&out[(size_t)gn0 * 128 + to * 8] = make_float4(e0[0], e0[1], e0[2], e0[3]);
        *(float4*)&out[(size_t)gn0 * 128 + to * 8 + 4] = make_float4(e0[4], e0[5], e0[6], e0[7]);
    }
    if (gn0 + 1 < N_PTS) {
        *(float4*)&out[(size_t)(gn0 + 1) * 128 + to * 8] = make_float4(e1[0], e1[1], e1[2], e1[3]);
        *(float4*)&out[(size_t)(gn0 + 1) * 128 + to * 8 + 4] = make_float4(e1[4], e1[5], e1[6], e1[7]);
    }
#pragma unroll
    for (int s = 1; s < 32; s <<= 1) {
#pragma unroll
        for (int c = 0; c < 8; ++c) lsum[c] += __shfl_xor(lsum[c], s);
    }
    if (tn == 0) {
        *(float4*)&m_part[(size_t)b * 128 + to * 8] = make_float4(mb[0], mb[1], mb[2], mb[3]);
        *(float4*)&m_part[(size_t)b * 128 + to * 8 + 4] = make_float4(mb[4], mb[5], mb[6], mb[7]);
        *(float4*)&l_part[(size_t)b * 128 + to * 8] = make_float4(lsum[0], lsum[1], lsum[2], lsum[3]);
        *(float4*)&l_part[(size_t)b * 128 + to * 8 + 4] = make_float4(lsum[4], lsum[5], lsum[6], lsum[7]);
    }
}

// ---------------- Kernel C2: combine (m,l) over blocks; emit scale[o][b] = exp(m_b - m)/l
__global__ __launch_bounds__(256) void kC2(const float* __restrict__ m_part,
                                           const float* __restrict__ l_part,
                                           float* __restrict__ scale) {
    const int o = blockIdx.x;
    const int tid = threadIdx.x;
    __shared__ float sm[256];
    float m = -3.4e38f;
    for (int b = tid; b < NB1; b += 256) m = fmaxf(m, m_part[(size_t)b * 128 + o]);
    sm[tid] = m;
    __syncthreads();
    for (int s = 128; s >= 1; s >>= 1) {
        if (tid < s) sm[tid] = fmaxf(sm[tid], sm[tid + s]);
        __syncthreads();
    }
    m = sm[0];
    __syncthreads();
    float l = 0.0f;
    for (int b = tid; b < NB1; b += 256)
        l += l_part[(size_t)b * 128 + o] * __expf(m_part[(size_t)b * 128 + o] - m);
    sm[tid] = l;
    __syncthreads();
    for (int s = 128; s >= 1; s >>= 1) {
        if (tid < s) sm[tid] += sm[tid + s];
        __syncthreads();
    }
    l = sm[0];
    float inv = 1.0f / l;
    for (int b = tid; b < NB1; b += 256)
        scale[(size_t)o * NB1 + b] = __expf(m_part[(size_t)b * 128 + o] - m) * inv;
}

// ---------------- Kernel C3: out[n][o] *= scale[o][n/64]
__global__ __launch_bounds__(256) void kC3(float* __restrict__ out,
                                           const float* __restrict__ scale) {
    const int b = blockIdx.x;
    const int tid = threadIdx.x;
    __shared__ float sc[128];
    if (tid < 128) sc[tid] = scale[(size_t)tid * NB1 + b];
    __syncthreads();
    const int n0 = b * TILE_N;
#pragma unroll
    for (int r = 0; r < 8; ++r) {
        int idx = (r * 256 + tid) * 4;   // [0,8192)
        int n = idx >> 7;
        int o = idx & 127;
        int gn = n0 + n;
        if (gn < N_PTS) {
            float4 v = *(float4*)&out[(size_t)gn * 128 + o];
            v.x *= sc[o];
            v.y *= sc[o + 1];
            v.z *= sc[o + 2];
            v.w *= sc[o + 3];
            *(float4*)&out[(size_t)gn * 128 + o] = v;
        }
    }
}

extern "C" void kernel_launch(void* const* d_in, const int* in_sizes, int n_in,
                              void* d_out, int out_size, void* d_ws, size_t ws_size,
                              hipStream_t stream) {
    const float* x = (const float*)d_in[0];       // (N, 128)
    const float* U = (const float*)d_in[1];       // (N, 128)
    const float* coeffs = (const float*)d_in[2];  // (128, 128, 128)
    float* out = (float*)d_out;                   // (N, 128)

    // workspace layout (floats)
    float* f = (float*)d_ws;
    float* spec = f;                         // 16384
    float* mixedT = spec + 16384;            // 16384
    float* m_part = mixedT + 16384;          // NB1*128
    float* l_part = m_part + (size_t)NB1 * 128;
    float* scale = l_part + (size_t)NB1 * 128;   // 128*NB1
    float* partialsA = scale + (size_t)128 * NB1;

    size_t fixed_bytes = ((size_t)(16384 * 2) + (size_t)NB1 * 128 * 3) * 4;
    int nA = 512;
    if (ws_size > fixed_bytes) {
        size_t avail = (ws_size - fixed_bytes) / 65536;   // 64KB per partial
        if ((size_t)nA > avail) nA = (int)avail;
    } else {
        nA = 1;
    }
    if (nA < 1) nA = 1;
    int chunk = (N_PTS + nA - 1) / nA;

    kA<<<nA, 256, 0, stream>>>(U, x, partialsA, chunk);
    kA2<<<64, 256, 0, stream>>>(partialsA, spec, nA);
    kB<<<4096, 256, 0, stream>>>(coeffs, spec, mixedT);
    kC1<<<NB1, 512, 0, stream>>>(U, mixedT, out, m_part, l_part);
    kC2<<<128, 256, 0, stream>>>(m_part, l_part, scale);
    kC3<<<NB1, 256, 0, stream>>>(out, scale);
}

// Round 3
// 275.662 us; speedup vs baseline: 15.5460x; 1.4593x over previous
//
#include <hip/hip_runtime.h>
#include <math.h>

#define N_PTS 100000
#define KDIM 128
#define CDIM 128          // IN_C == OUT_C == 128
#define TILE_N 64
#define NB1 ((N_PTS + TILE_N - 1) / TILE_N)   // 1563 C1 blocks

// ---------------- Kernel A: spec partials: partials[b][k][i] = sum over block-b's n-chunk of U[n,k]*x[n,i]
__global__ __launch_bounds__(256) void kA(const float* __restrict__ U,
                                          const float* __restrict__ x,
                                          float* __restrict__ partials,
                                          int chunk) {
    __shared__ float Us[32 * 128];
    __shared__ float Xs[32 * 128];
    const int tid = threadIdx.x;
    const int b = blockIdx.x;
    const int n_begin = b * chunk;
    const int n_end = min(N_PTS, n_begin + chunk);
    const int tk = tid >> 4;      // 0..15 -> k block
    const int ti = tid & 15;      // 0..15 -> i block
    float acc[8][8];
#pragma unroll
    for (int a = 0; a < 8; ++a)
#pragma unroll
        for (int c = 0; c < 8; ++c) acc[a][c] = 0.0f;

    for (int n0 = n_begin; n0 < n_end; n0 += 32) {
#pragma unroll
        for (int r = 0; r < 4; ++r) {
            int idx = (r * 256 + tid) * 4;   // [0,4096)
            int n = idx >> 7;
            int k = idx & 127;
            int gn = n0 + n;
            float4 u4 = make_float4(0, 0, 0, 0), x4 = make_float4(0, 0, 0, 0);
            if (gn < n_end) {
                u4 = *(const float4*)&U[(size_t)gn * 128 + k];
                x4 = *(const float4*)&x[(size_t)gn * 128 + k];
            }
            *(float4*)&Us[n * 128 + k] = u4;
            *(float4*)&Xs[n * 128 + k] = x4;
        }
        __syncthreads();
        int nn = min(32, n_end - n0);
        for (int n = 0; n < nn; ++n) {
            float4 ua = *(float4*)&Us[n * 128 + tk * 8];
            float4 ub = *(float4*)&Us[n * 128 + tk * 8 + 4];
            float4 xa = *(float4*)&Xs[n * 128 + ti * 8];
            float4 xb = *(float4*)&Xs[n * 128 + ti * 8 + 4];
            float u[8] = {ua.x, ua.y, ua.z, ua.w, ub.x, ub.y, ub.z, ub.w};
            float xv[8] = {xa.x, xa.y, xa.z, xa.w, xb.x, xb.y, xb.z, xb.w};
#pragma unroll
            for (int a = 0; a < 8; ++a)
#pragma unroll
                for (int c = 0; c < 8; ++c) acc[a][c] += u[a] * xv[c];
        }
        __syncthreads();
    }
    float* p = partials + (size_t)b * 16384;
#pragma unroll
    for (int a = 0; a < 8; ++a)
#pragma unroll
        for (int c = 0; c < 8; c += 4) {
            *(float4*)&p[(tk * 8 + a) * 128 + ti * 8 + c] =
                make_float4(acc[a][c], acc[a][c + 1], acc[a][c + 2], acc[a][c + 3]);
        }
}

// ---------------- Kernel A2a: partial2[s][j] = sum of partials[b][j] over this s-slice of b
// grid = 64 jc-groups x 8 s-slices; fully coalesced; 4 accumulators for ILP.
__global__ __launch_bounds__(256) void kA2a(const float* __restrict__ partials,
                                            float* __restrict__ partial2, int nA) {
    const int jc = blockIdx.x >> 3;
    const int s = blockIdx.x & 7;
    const int j = jc * 256 + threadIdx.x;
    const int per = (nA + 7) >> 3;
    int b = s * per;
    const int be = min(b + per, nA);
    float a0 = 0.0f, a1 = 0.0f, a2 = 0.0f, a3 = 0.0f;
    for (; b + 4 <= be; b += 4) {
        a0 += partials[(size_t)(b + 0) * 16384 + j];
        a1 += partials[(size_t)(b + 1) * 16384 + j];
        a2 += partials[(size_t)(b + 2) * 16384 + j];
        a3 += partials[(size_t)(b + 3) * 16384 + j];
    }
    for (; b < be; ++b) a0 += partials[(size_t)b * 16384 + j];
    partial2[(size_t)s * 16384 + j] = (a0 + a1) + (a2 + a3);
}

// ---------------- Kernel A2b: spec[j] = sum_s partial2[s][j]  (8 independent loads, all in flight)
__global__ __launch_bounds__(256) void kA2b(const float* __restrict__ partial2,
                                            float* __restrict__ spec) {
    int j = blockIdx.x * 256 + threadIdx.x;   // grid 64 -> j in [0,16384)
    float v0 = partial2[j];
    float v1 = partial2[16384 + j];
    float v2 = partial2[2 * 16384 + j];
    float v3 = partial2[3 * 16384 + j];
    float v4 = partial2[4 * 16384 + j];
    float v5 = partial2[5 * 16384 + j];
    float v6 = partial2[6 * 16384 + j];
    float v7 = partial2[7 * 16384 + j];
    spec[j] = ((v0 + v1) + (v2 + v3)) + ((v4 + v5) + (v6 + v7));
}

// ---------------- Kernel B: mixedT[k][o] = sum_i coeffs[o][k][i]*spec[k][i]; one wave per (o,k)
__global__ __launch_bounds__(256) void kB(const float* __restrict__ coeffs,
                                          const float* __restrict__ spec,
                                          float* __restrict__ mixedT) {
    int wave = (blockIdx.x * 256 + threadIdx.x) >> 6;   // [0, 16384)
    int lane = threadIdx.x & 63;
    int o = wave >> 7;
    int k = wave & 127;
    float2 c2 = *(const float2*)&coeffs[((size_t)o * 128 + k) * 128 + lane * 2];
    float2 s2 = *(const float2*)&spec[k * 128 + lane * 2];
    float v = c2.x * s2.x + c2.y * s2.y;
#pragma unroll
    for (int s = 32; s >= 1; s >>= 1) v += __shfl_xor(v, s);
    if (lane == 0) mixedT[k * 128 + o] = v;
}

// ---------------- Kernel C1: logits tile (64n x 128o), fused local softmax stats.
// 512 threads; per-thread 2n x 8o (acc = 16 VGPR). Softmax stats via shfl
// butterfly over the 32 tn-lanes (each half-wave spans all 64 n). No LDS
// reduction scratch. Writes exp(logit - m_block) to out; (m,l) partials to ws.
__global__ __launch_bounds__(512) void kC1(const float* __restrict__ U,
                                           const float* __restrict__ mixedT,
                                           float* __restrict__ out,
                                           float* __restrict__ m_part,
                                           float* __restrict__ l_part) {
    __shared__ float Ut[128 * 66];    // [k][n], stride 66 (b64-read conflict-free, 8B aligned)
    __shared__ float Mx[32 * 128];    // mixedT k-chunk [kk][o]
    const int tid = threadIdx.x;
    const int b = blockIdx.x;
    const int n0 = b * TILE_N;
    const int tn = tid & 31;    // n pair index: rows 2*tn, 2*tn+1
    const int to = tid >> 5;    // o group: 8 o's at to*8

    // ---- stage U transposed: issue 4 float4 loads, then 16 scalar LDS writes
    float4 uv[4];
#pragma unroll
    for (int r = 0; r < 4; ++r) {
        int idx = (r * 512 + tid) * 4;   // [0,8192)
        int n = idx >> 7;
        int k = idx & 127;
        int gn = n0 + n;
        uv[r] = (gn < N_PTS) ? *(const float4*)&U[(size_t)gn * 128 + k]
                             : make_float4(0, 0, 0, 0);
    }
#pragma unroll
    for (int r = 0; r < 4; ++r) {
        int idx = (r * 512 + tid) * 4;
        int n = idx >> 7;
        int k = idx & 127;
        Ut[(k + 0) * 66 + n] = uv[r].x;
        Ut[(k + 1) * 66 + n] = uv[r].y;
        Ut[(k + 2) * 66 + n] = uv[r].z;
        Ut[(k + 3) * 66 + n] = uv[r].w;
    }

    float acc0[8], acc1[8];
#pragma unroll
    for (int c = 0; c < 8; ++c) { acc0[c] = 0.0f; acc1[c] = 0.0f; }

    for (int kc = 0; kc < 128; kc += 32) {
        __syncthreads();   // Ut staging done (first iter) / Mx no longer in use (later)
#pragma unroll
        for (int r = 0; r < 2; ++r) {
            int idx = (r * 512 + tid) * 4;   // [0,4096)
            int kk = idx >> 7;
            int o = idx & 127;
            *(float4*)&Mx[kk * 128 + o] = *(const float4*)&mixedT[(kc + kk) * 128 + o];
        }
        __syncthreads();
        for (int k = 0; k < 32; ++k) {
            float2 u2 = *(float2*)&Ut[(kc + k) * 66 + tn * 2];
            float4 m0 = *(float4*)&Mx[k * 128 + to * 8];
            float4 m1 = *(float4*)&Mx[k * 128 + to * 8 + 4];
            float mm[8] = {m0.x, m0.y, m0.z, m0.w, m1.x, m1.y, m1.z, m1.w};
#pragma unroll
            for (int c = 0; c < 8; ++c) {
                acc0[c] += u2.x * mm[c];
                acc1[c] += u2.y * mm[c];
            }
        }
    }

    // ---- tail guard
    const int gn0 = n0 + tn * 2;
    if (gn0 >= N_PTS) {
#pragma unroll
        for (int c = 0; c < 8; ++c) acc0[c] = -3.4e38f;
    }
    if (gn0 + 1 >= N_PTS) {
#pragma unroll
        for (int c = 0; c < 8; ++c) acc1[c] = -3.4e38f;
    }

    // ---- per-o tile max: butterfly over 32 tn-lanes (same half-wave, same to)
    float mb[8];
#pragma unroll
    for (int c = 0; c < 8; ++c) mb[c] = fmaxf(acc0[c], acc1[c]);
#pragma unroll
    for (int s = 1; s < 32; s <<= 1) {
#pragma unroll
        for (int c = 0; c < 8; ++c) mb[c] = fmaxf(mb[c], __shfl_xor(mb[c], s));
    }

    // ---- exp, write unnormalized, butterfly local sum
    float e0[8], e1[8], lsum[8];
#pragma unroll
    for (int c = 0; c < 8; ++c) {
        e0[c] = __expf(acc0[c] - mb[c]);
        e1[c] = __expf(acc1[c] - mb[c]);
        lsum[c] = e0[c] + e1[c];
    }
    if (gn0 < N_PTS) {
        *(float4*)&out[(size_t)gn0 * 128 + to * 8] = make_float4(e0[0], e0[1], e0[2], e0[3]);
        *(float4*)&out[(size_t)gn0 * 128 + to * 8 + 4] = make_float4(e0[4], e0[5], e0[6], e0[7]);
    }
    if (gn0 + 1 < N_PTS) {
        *(float4*)&out[(size_t)(gn0 + 1) * 128 + to * 8] = make_float4(e1[0], e1[1], e1[2], e1[3]);
        *(float4*)&out[(size_t)(gn0 + 1) * 128 + to * 8 + 4] = make_float4(e1[4], e1[5], e1[6], e1[7]);
    }
#pragma unroll
    for (int s = 1; s < 32; s <<= 1) {
#pragma unroll
        for (int c = 0; c < 8; ++c) lsum[c] += __shfl_xor(lsum[c], s);
    }
    if (tn == 0) {
        *(float4*)&m_part[(size_t)b * 128 + to * 8] = make_float4(mb[0], mb[1], mb[2], mb[3]);
        *(float4*)&m_part[(size_t)b * 128 + to * 8 + 4] = make_float4(mb[4], mb[5], mb[6], mb[7]);
        *(float4*)&l_part[(size_t)b * 128 + to * 8] = make_float4(lsum[0], lsum[1], lsum[2], lsum[3]);
        *(float4*)&l_part[(size_t)b * 128 + to * 8 + 4] = make_float4(lsum[4], lsum[5], lsum[6], lsum[7]);
    }
}

// ---------------- Kernel C2: combine (m,l) over blocks; emit scale[o][b] = exp(m_b - m)/l
__global__ __launch_bounds__(256) void kC2(const float* __restrict__ m_part,
                                           const float* __restrict__ l_part,
                                           float* __restrict__ scale) {
    const int o = blockIdx.x;
    const int tid = threadIdx.x;
    __shared__ float sm[256];
    float m = -3.4e38f;
    for (int b = tid; b < NB1; b += 256) m = fmaxf(m, m_part[(size_t)b * 128 + o]);
    sm[tid] = m;
    __syncthreads();
    for (int s = 128; s >= 1; s >>= 1) {
        if (tid < s) sm[tid] = fmaxf(sm[tid], sm[tid + s]);
        __syncthreads();
    }
    m = sm[0];
    __syncthreads();
    float l = 0.0f;
    for (int b = tid; b < NB1; b += 256)
        l += l_part[(size_t)b * 128 + o] * __expf(m_part[(size_t)b * 128 + o] - m);
    sm[tid] = l;
    __syncthreads();
    for (int s = 128; s >= 1; s >>= 1) {
        if (tid < s) sm[tid] += sm[tid + s];
        __syncthreads();
    }
    l = sm[0];
    float inv = 1.0f / l;
    for (int b = tid; b < NB1; b += 256)
        scale[(size_t)o * NB1 + b] = __expf(m_part[(size_t)b * 128 + o] - m) * inv;
}

// ---------------- Kernel C3: out[n][o] *= scale[o][n/64]
__global__ __launch_bounds__(256) void kC3(float* __restrict__ out,
                                           const float* __restrict__ scale) {
    const int b = blockIdx.x;
    const int tid = threadIdx.x;
    __shared__ float sc[128];
    if (tid < 128) sc[tid] = scale[(size_t)tid * NB1 + b];
    __syncthreads();
    const int n0 = b * TILE_N;
#pragma unroll
    for (int r = 0; r < 8; ++r) {
        int idx = (r * 256 + tid) * 4;   // [0,8192)
        int n = idx >> 7;
        int o = idx & 127;
        int gn = n0 + n;
        if (gn < N_PTS) {
            float4 v = *(float4*)&out[(size_t)gn * 128 + o];
            v.x *= sc[o];
            v.y *= sc[o + 1];
            v.z *= sc[o + 2];
            v.w *= sc[o + 3];
            *(float4*)&out[(size_t)gn * 128 + o] = v;
        }
    }
}

extern "C" void kernel_launch(void* const* d_in, const int* in_sizes, int n_in,
                              void* d_out, int out_size, void* d_ws, size_t ws_size,
                              hipStream_t stream) {
    const float* x = (const float*)d_in[0];       // (N, 128)
    const float* U = (const float*)d_in[1];       // (N, 128)
    const float* coeffs = (const float*)d_in[2];  // (128, 128, 128)
    float* out = (float*)d_out;                   // (N, 128)

    // workspace layout (floats)
    float* f = (float*)d_ws;
    float* spec = f;                         // 16384
    float* mixedT = spec + 16384;            // 16384
    float* m_part = mixedT + 16384;          // NB1*128
    float* l_part = m_part + (size_t)NB1 * 128;
    float* scale = l_part + (size_t)NB1 * 128;   // 128*NB1
    float* partial2 = scale + (size_t)128 * NB1; // 8*16384
    float* partialsA = partial2 + 8 * 16384;

    size_t fixed_bytes = ((size_t)(16384 * 2) + (size_t)NB1 * 128 * 3 + (size_t)8 * 16384) * 4;
    int nA = 512;
    if (ws_size > fixed_bytes) {
        size_t avail = (ws_size - fixed_bytes) / 65536;   // 64KB per partial
        if ((size_t)nA > avail) nA = (int)avail;
    } else {
        nA = 1;
    }
    if (nA < 1) nA = 1;
    int chunk = (N_PTS + nA - 1) / nA;

    kA<<<nA, 256, 0, stream>>>(U, x, partialsA, chunk);
    kA2a<<<512, 256, 0, stream>>>(partialsA, partial2, nA);
    kA2b<<<64, 256, 0, stream>>>(partial2, spec);
    kB<<<4096, 256, 0, stream>>>(coeffs, spec, mixedT);
    kC1<<<NB1, 512, 0, stream>>>(U, mixedT, out, m_part, l_part);
    kC2<<<128, 256, 0, stream>>>(m_part, l_part, scale);
    kC3<<<NB1, 256, 0, stream>>>(out, scale);
}

// Round 4
// 261.195 us; speedup vs baseline: 16.4070x; 1.0554x over previous
//
#include <hip/hip_runtime.h>
#include <math.h>

#define N_PTS 100000
#define KDIM 128
#define CDIM 128          // IN_C == OUT_C == 128
#define TILE_N 64
#define NB1 ((N_PTS + TILE_N - 1) / TILE_N)   // 1563 C1 blocks

// ---------------- Kernel A: spec partials: partials[b][k][i] = sum over block-b's n-chunk of U[n,k]*x[n,i]
__global__ __launch_bounds__(256) void kA(const float* __restrict__ U,
                                          const float* __restrict__ x,
                                          float* __restrict__ partials,
                                          int chunk) {
    __shared__ float Us[32 * 128];
    __shared__ float Xs[32 * 128];
    const int tid = threadIdx.x;
    const int b = blockIdx.x;
    const int n_begin = b * chunk;
    const int n_end = min(N_PTS, n_begin + chunk);
    const int tk = tid >> 4;      // 0..15 -> k block
    const int ti = tid & 15;      // 0..15 -> i block
    float acc[8][8];
#pragma unroll
    for (int a = 0; a < 8; ++a)
#pragma unroll
        for (int c = 0; c < 8; ++c) acc[a][c] = 0.0f;

    for (int n0 = n_begin; n0 < n_end; n0 += 32) {
#pragma unroll
        for (int r = 0; r < 4; ++r) {
            int idx = (r * 256 + tid) * 4;   // [0,4096)
            int n = idx >> 7;
            int k = idx & 127;
            int gn = n0 + n;
            float4 u4 = make_float4(0, 0, 0, 0), x4 = make_float4(0, 0, 0, 0);
            if (gn < n_end) {
                u4 = *(const float4*)&U[(size_t)gn * 128 + k];
                x4 = *(const float4*)&x[(size_t)gn * 128 + k];
            }
            *(float4*)&Us[n * 128 + k] = u4;
            *(float4*)&Xs[n * 128 + k] = x4;
        }
        __syncthreads();
        int nn = min(32, n_end - n0);
        for (int n = 0; n < nn; ++n) {
            float4 ua = *(float4*)&Us[n * 128 + tk * 8];
            float4 ub = *(float4*)&Us[n * 128 + tk * 8 + 4];
            float4 xa = *(float4*)&Xs[n * 128 + ti * 8];
            float4 xb = *(float4*)&Xs[n * 128 + ti * 8 + 4];
            float u[8] = {ua.x, ua.y, ua.z, ua.w, ub.x, ub.y, ub.z, ub.w};
            float xv[8] = {xa.x, xa.y, xa.z, xa.w, xb.x, xb.y, xb.z, xb.w};
#pragma unroll
            for (int a = 0; a < 8; ++a)
#pragma unroll
                for (int c = 0; c < 8; ++c) acc[a][c] += u[a] * xv[c];
        }
        __syncthreads();
    }
    float* p = partials + (size_t)b * 16384;
#pragma unroll
    for (int a = 0; a < 8; ++a)
#pragma unroll
        for (int c = 0; c < 8; c += 4) {
            *(float4*)&p[(tk * 8 + a) * 128 + ti * 8 + c] =
                make_float4(acc[a][c], acc[a][c + 1], acc[a][c + 2], acc[a][c + 3]);
        }
}

// ---------------- Kernel A2a: partial2[s][j] = sum of partials[b][j] over this s-slice of b
__global__ __launch_bounds__(256) void kA2a(const float* __restrict__ partials,
                                            float* __restrict__ partial2, int nA) {
    const int jc = blockIdx.x >> 3;
    const int s = blockIdx.x & 7;
    const int j = jc * 256 + threadIdx.x;
    const int per = (nA + 7) >> 3;
    int b = s * per;
    const int be = min(b + per, nA);
    float a0 = 0.0f, a1 = 0.0f, a2 = 0.0f, a3 = 0.0f;
    for (; b + 4 <= be; b += 4) {
        a0 += partials[(size_t)(b + 0) * 16384 + j];
        a1 += partials[(size_t)(b + 1) * 16384 + j];
        a2 += partials[(size_t)(b + 2) * 16384 + j];
        a3 += partials[(size_t)(b + 3) * 16384 + j];
    }
    for (; b < be; ++b) a0 += partials[(size_t)b * 16384 + j];
    partial2[(size_t)s * 16384 + j] = (a0 + a1) + (a2 + a3);
}

// ---------------- Kernel A2b: spec[j] = sum_s partial2[s][j]
__global__ __launch_bounds__(256) void kA2b(const float* __restrict__ partial2,
                                            float* __restrict__ spec) {
    int j = blockIdx.x * 256 + threadIdx.x;
    float v0 = partial2[j];
    float v1 = partial2[16384 + j];
    float v2 = partial2[2 * 16384 + j];
    float v3 = partial2[3 * 16384 + j];
    float v4 = partial2[4 * 16384 + j];
    float v5 = partial2[5 * 16384 + j];
    float v6 = partial2[6 * 16384 + j];
    float v7 = partial2[7 * 16384 + j];
    spec[j] = ((v0 + v1) + (v2 + v3)) + ((v4 + v5) + (v6 + v7));
}

// ---------------- Kernel B: mixedT[k][o] = sum_i coeffs[o][k][i]*spec[k][i]; one wave per (o,k)
__global__ __launch_bounds__(256) void kB(const float* __restrict__ coeffs,
                                          const float* __restrict__ spec,
                                          float* __restrict__ mixedT) {
    int wave = (blockIdx.x * 256 + threadIdx.x) >> 6;   // [0, 16384)
    int lane = threadIdx.x & 63;
    int o = wave >> 7;
    int k = wave & 127;
    float2 c2 = *(const float2*)&coeffs[((size_t)o * 128 + k) * 128 + lane * 2];
    float2 s2 = *(const float2*)&spec[k * 128 + lane * 2];
    float v = c2.x * s2.x + c2.y * s2.y;
#pragma unroll
    for (int s = 32; s >= 1; s >>= 1) v += __shfl_xor(v, s);
    if (lane == 0) mixedT[k * 128 + o] = v;
}

// ---------------- Kernel C1 (v3): 64n x 128o tile, BARRIER-FREE K-loop.
// 512 threads = 8 waves. Wave w owns o in [w*16, w*16+16); lane l owns row n0+l.
// mixedT fragment address is wave-uniform -> scalar loads, no LDS staging for it.
// Per k: 1 ds_read_b32 (Ut, 64 consecutive floats = conflict-free) + 16 FMA.
// LDS = 33.8 KB -> 4 blocks/CU -> 32 waves/CU.
// m_part/l_part stored [o][b] so kC2 is coalesced.
__global__ __launch_bounds__(512) void kC1(const float* __restrict__ U,
                                           const float* __restrict__ mixedT,
                                           float* __restrict__ out,
                                           float* __restrict__ m_part,
                                           float* __restrict__ l_part) {
    __shared__ float Ut[128 * 66];    // [k][n], stride 66
    const int tid = threadIdx.x;
    const int b = blockIdx.x;
    const int n0 = b * TILE_N;
    const int lane = tid & 63;
    const int wv = __builtin_amdgcn_readfirstlane(tid >> 6);   // wave id 0..7 (SGPR)
    const int ob = wv * 16;                                     // o base for this wave

    // ---- stage U transposed (once)
    float4 uv[4];
#pragma unroll
    for (int r = 0; r < 4; ++r) {
        int idx = (r * 512 + tid) * 4;   // [0,8192)
        int n = idx >> 7;
        int k = idx & 127;
        int gn = n0 + n;
        uv[r] = (gn < N_PTS) ? *(const float4*)&U[(size_t)gn * 128 + k]
                             : make_float4(0, 0, 0, 0);
    }
#pragma unroll
    for (int r = 0; r < 4; ++r) {
        int idx = (r * 512 + tid) * 4;
        int n = idx >> 7;
        int k = idx & 127;
        Ut[(k + 0) * 66 + n] = uv[r].x;
        Ut[(k + 1) * 66 + n] = uv[r].y;
        Ut[(k + 2) * 66 + n] = uv[r].z;
        Ut[(k + 3) * 66 + n] = uv[r].w;
    }
    __syncthreads();   // the ONLY barrier

    float acc[16];
#pragma unroll
    for (int c = 0; c < 16; ++c) acc[c] = 0.0f;

    const float* __restrict__ mrow = mixedT + ob;
#pragma unroll 4
    for (int k = 0; k < 128; ++k) {
        float u = Ut[k * 66 + lane];
        const float* __restrict__ m = mrow + k * 128;   // wave-uniform address
#pragma unroll
        for (int c = 0; c < 16; ++c) acc[c] = fmaf(m[c], u, acc[c]);
    }

    // ---- tail guard
    const int gn = n0 + lane;
    if (gn >= N_PTS) {
#pragma unroll
        for (int c = 0; c < 16; ++c) acc[c] = -3.4e38f;
    }

    // ---- per-o tile max over 64 lanes (n-dim)
    float mb[16];
#pragma unroll
    for (int c = 0; c < 16; ++c) mb[c] = acc[c];
#pragma unroll
    for (int s = 1; s < 64; s <<= 1) {
#pragma unroll
        for (int c = 0; c < 16; ++c) mb[c] = fmaxf(mb[c], __shfl_xor(mb[c], s));
    }

    // ---- exp in place, write unnormalized
#pragma unroll
    for (int c = 0; c < 16; ++c) acc[c] = __expf(acc[c] - mb[c]);
    if (gn < N_PTS) {
#pragma unroll
        for (int c = 0; c < 16; c += 4)
            *(float4*)&out[(size_t)gn * 128 + ob + c] =
                make_float4(acc[c], acc[c + 1], acc[c + 2], acc[c + 3]);
    }

    // ---- local sum over 64 lanes
    float ls[16];
#pragma unroll
    for (int c = 0; c < 16; ++c) ls[c] = acc[c];
#pragma unroll
    for (int s = 1; s < 64; s <<= 1) {
#pragma unroll
        for (int c = 0; c < 16; ++c) ls[c] += __shfl_xor(ls[c], s);
    }
    if (lane == 0) {
#pragma unroll
        for (int c = 0; c < 16; ++c) {
            m_part[(size_t)(ob + c) * NB1 + b] = mb[c];
            l_part[(size_t)(ob + c) * NB1 + b] = ls[c];
        }
    }
}

// ---------------- Kernel C2: combine (m,l) over blocks; [o][b] layout -> coalesced
__global__ __launch_bounds__(256) void kC2(const float* __restrict__ m_part,
                                           const float* __restrict__ l_part,
                                           float* __restrict__ scale) {
    const int o = blockIdx.x;
    const int tid = threadIdx.x;
    const float* __restrict__ mp = m_part + (size_t)o * NB1;
    const float* __restrict__ lp = l_part + (size_t)o * NB1;
    __shared__ float sm[256];
    float m = -3.4e38f;
    for (int b = tid; b < NB1; b += 256) m = fmaxf(m, mp[b]);
    sm[tid] = m;
    __syncthreads();
    for (int s = 128; s >= 1; s >>= 1) {
        if (tid < s) sm[tid] = fmaxf(sm[tid], sm[tid + s]);
        __syncthreads();
    }
    m = sm[0];
    __syncthreads();
    float l = 0.0f;
    for (int b = tid; b < NB1; b += 256)
        l += lp[b] * __expf(mp[b] - m);
    sm[tid] = l;
    __syncthreads();
    for (int s = 128; s >= 1; s >>= 1) {
        if (tid < s) sm[tid] += sm[tid + s];
        __syncthreads();
    }
    l = sm[0];
    float inv = 1.0f / l;
    for (int b = tid; b < NB1; b += 256)
        scale[(size_t)o * NB1 + b] = __expf(mp[b] - m) * inv;
}

// ---------------- Kernel C3: out[n][o] *= scale[o][n/64]
__global__ __launch_bounds__(256) void kC3(float* __restrict__ out,
                                           const float* __restrict__ scale) {
    const int b = blockIdx.x;
    const int tid = threadIdx.x;
    __shared__ float sc[128];
    if (tid < 128) sc[tid] = scale[(size_t)tid * NB1 + b];
    __syncthreads();
    const int n0 = b * TILE_N;
#pragma unroll
    for (int r = 0; r < 8; ++r) {
        int idx = (r * 256 + tid) * 4;   // [0,8192)
        int n = idx >> 7;
        int o = idx & 127;
        int gn = n0 + n;
        if (gn < N_PTS) {
            float4 v = *(float4*)&out[(size_t)gn * 128 + o];
            v.x *= sc[o];
            v.y *= sc[o + 1];
            v.z *= sc[o + 2];
            v.w *= sc[o + 3];
            *(float4*)&out[(size_t)gn * 128 + o] = v;
        }
    }
}

extern "C" void kernel_launch(void* const* d_in, const int* in_sizes, int n_in,
                              void* d_out, int out_size, void* d_ws, size_t ws_size,
                              hipStream_t stream) {
    const float* x = (const float*)d_in[0];       // (N, 128)
    const float* U = (const float*)d_in[1];       // (N, 128)
    const float* coeffs = (const float*)d_in[2];  // (128, 128, 128)
    float* out = (float*)d_out;                   // (N, 128)

    // workspace layout (floats)
    float* f = (float*)d_ws;
    float* spec = f;                         // 16384
    float* mixedT = spec + 16384;            // 16384
    float* m_part = mixedT + 16384;          // 128*NB1  ([o][b])
    float* l_part = m_part + (size_t)128 * NB1;
    float* scale = l_part + (size_t)128 * NB1;   // 128*NB1
    float* partial2 = scale + (size_t)128 * NB1; // 8*16384
    float* partialsA = partial2 + 8 * 16384;

    size_t fixed_bytes = ((size_t)(16384 * 2) + (size_t)NB1 * 128 * 3 + (size_t)8 * 16384) * 4;
    int nA = 512;
    if (ws_size > fixed_bytes) {
        size_t avail = (ws_size - fixed_bytes) / 65536;   // 64KB per partial
        if ((size_t)nA > avail) nA = (int)avail;
    } else {
        nA = 1;
    }
    if (nA < 1) nA = 1;
    int chunk = (N_PTS + nA - 1) / nA;

    kA<<<nA, 256, 0, stream>>>(U, x, partialsA, chunk);
    kA2a<<<512, 256, 0, stream>>>(partialsA, partial2, nA);
    kA2b<<<64, 256, 0, stream>>>(partial2, spec);
    kB<<<4096, 256, 0, stream>>>(coeffs, spec, mixedT);
    kC1<<<NB1, 512, 0, stream>>>(U, mixedT, out, m_part, l_part);
    kC2<<<128, 256, 0, stream>>>(m_part, l_part, scale);
    kC3<<<NB1, 256, 0, stream>>>(out, scale);
}

// Round 5
// 230.790 us; speedup vs baseline: 18.5686x; 1.1317x over previous
//
#include <hip/hip_runtime.h>
#include <math.h>

#define N_PTS 100000
#define KDIM 128
#define CDIM 128          // IN_C == OUT_C == 128
#define TILE_N 64
#define NB1 ((N_PTS + TILE_N - 1) / TILE_N)   // 1563 C1 blocks

typedef short s16x8 __attribute__((ext_vector_type(8)));
typedef float f32x4 __attribute__((ext_vector_type(4)));

// round-to-nearest-even float -> bf16 bits
static __device__ __forceinline__ unsigned short f2bf(float f) {
    unsigned int u = __float_as_uint(f);
    unsigned int r = (u + 0x7FFFu + ((u >> 16) & 1u)) >> 16;
    return (unsigned short)r;
}
static __device__ __forceinline__ float bf2f(unsigned short h) {
    return __uint_as_float(((unsigned int)h) << 16);
}

// ---------------- Kernel A: spec partials: partials[b][k][i] = sum over block-b's n-chunk of U[n,k]*x[n,i]
__global__ __launch_bounds__(256) void kA(const float* __restrict__ U,
                                          const float* __restrict__ x,
                                          float* __restrict__ partials,
                                          int chunk) {
    __shared__ float Us[32 * 128];
    __shared__ float Xs[32 * 128];
    const int tid = threadIdx.x;
    const int b = blockIdx.x;
    const int n_begin = b * chunk;
    const int n_end = min(N_PTS, n_begin + chunk);
    const int tk = tid >> 4;      // 0..15 -> k block
    const int ti = tid & 15;      // 0..15 -> i block
    float acc[8][8];
#pragma unroll
    for (int a = 0; a < 8; ++a)
#pragma unroll
        for (int c = 0; c < 8; ++c) acc[a][c] = 0.0f;

    for (int n0 = n_begin; n0 < n_end; n0 += 32) {
#pragma unroll
        for (int r = 0; r < 4; ++r) {
            int idx = (r * 256 + tid) * 4;   // [0,4096)
            int n = idx >> 7;
            int k = idx & 127;
            int gn = n0 + n;
            float4 u4 = make_float4(0, 0, 0, 0), x4 = make_float4(0, 0, 0, 0);
            if (gn < n_end) {
                u4 = *(const float4*)&U[(size_t)gn * 128 + k];
                x4 = *(const float4*)&x[(size_t)gn * 128 + k];
            }
            *(float4*)&Us[n * 128 + k] = u4;
            *(float4*)&Xs[n * 128 + k] = x4;
        }
        __syncthreads();
        int nn = min(32, n_end - n0);
        for (int n = 0; n < nn; ++n) {
            float4 ua = *(float4*)&Us[n * 128 + tk * 8];
            float4 ub = *(float4*)&Us[n * 128 + tk * 8 + 4];
            float4 xa = *(float4*)&Xs[n * 128 + ti * 8];
            float4 xb = *(float4*)&Xs[n * 128 + ti * 8 + 4];
            float u[8] = {ua.x, ua.y, ua.z, ua.w, ub.x, ub.y, ub.z, ub.w};
            float xv[8] = {xa.x, xa.y, xa.z, xa.w, xb.x, xb.y, xb.z, xb.w};
#pragma unroll
            for (int a = 0; a < 8; ++a)
#pragma unroll
                for (int c = 0; c < 8; ++c) acc[a][c] += u[a] * xv[c];
        }
        __syncthreads();
    }
    float* p = partials + (size_t)b * 16384;
#pragma unroll
    for (int a = 0; a < 8; ++a)
#pragma unroll
        for (int c = 0; c < 8; c += 4) {
            *(float4*)&p[(tk * 8 + a) * 128 + ti * 8 + c] =
                make_float4(acc[a][c], acc[a][c + 1], acc[a][c + 2], acc[a][c + 3]);
        }
}

// ---------------- Kernel A2a: partial2[s][j] = sum of partials[b][j] over this s-slice of b
__global__ __launch_bounds__(256) void kA2a(const float* __restrict__ partials,
                                            float* __restrict__ partial2, int nA) {
    const int jc = blockIdx.x >> 3;
    const int s = blockIdx.x & 7;
    const int j = jc * 256 + threadIdx.x;
    const int per = (nA + 7) >> 3;
    int b = s * per;
    const int be = min(b + per, nA);
    float a0 = 0.0f, a1 = 0.0f, a2 = 0.0f, a3 = 0.0f;
    for (; b + 4 <= be; b += 4) {
        a0 += partials[(size_t)(b + 0) * 16384 + j];
        a1 += partials[(size_t)(b + 1) * 16384 + j];
        a2 += partials[(size_t)(b + 2) * 16384 + j];
        a3 += partials[(size_t)(b + 3) * 16384 + j];
    }
    for (; b < be; ++b) a0 += partials[(size_t)b * 16384 + j];
    partial2[(size_t)s * 16384 + j] = (a0 + a1) + (a2 + a3);
}

// ---------------- Kernel A2b: spec[j] = sum_s partial2[s][j]
__global__ __launch_bounds__(256) void kA2b(const float* __restrict__ partial2,
                                            float* __restrict__ spec) {
    int j = blockIdx.x * 256 + threadIdx.x;
    float v0 = partial2[j];
    float v1 = partial2[16384 + j];
    float v2 = partial2[2 * 16384 + j];
    float v3 = partial2[3 * 16384 + j];
    float v4 = partial2[4 * 16384 + j];
    float v5 = partial2[5 * 16384 + j];
    float v6 = partial2[6 * 16384 + j];
    float v7 = partial2[7 * 16384 + j];
    spec[j] = ((v0 + v1) + (v2 + v3)) + ((v4 + v5) + (v6 + v7));
}

// ---------------- Kernel B: mixed[o][k] = sum_i coeffs[o][k][i]*spec[k][i]; one wave per (o,k).
// Emits bf16 hi/lo of mixed in A-FRAGMENT order for kC1:
//   idx = ((o>>4)*4 + (k>>5))*512 + (((k>>3)&3)*16 + (o&15))*8 + (k&7)
__global__ __launch_bounds__(256) void kB(const float* __restrict__ coeffs,
                                          const float* __restrict__ spec,
                                          unsigned short* __restrict__ afrag_hi,
                                          unsigned short* __restrict__ afrag_lo) {
    int wave = (blockIdx.x * 256 + threadIdx.x) >> 6;   // [0, 16384)
    int lane = threadIdx.x & 63;
    int o = wave >> 7;
    int k = wave & 127;
    float2 c2 = *(const float2*)&coeffs[((size_t)o * 128 + k) * 128 + lane * 2];
    float2 s2 = *(const float2*)&spec[k * 128 + lane * 2];
    float v = c2.x * s2.x + c2.y * s2.y;
#pragma unroll
    for (int s = 32; s >= 1; s >>= 1) v += __shfl_xor(v, s);
    if (lane == 0) {
        unsigned short hi = f2bf(v);
        unsigned short lo = f2bf(v - bf2f(hi));
        int idx = ((o >> 4) * 4 + (k >> 5)) * 512 + (((k >> 3) & 3) * 16 + (o & 15)) * 8 + (k & 7);
        afrag_hi[idx] = hi;
        afrag_lo[idx] = lo;
    }
}

// ---------------- Kernel C1 (MFMA): 64n x 128o tile via bf16x2 split (hi*hi + hi*lo + lo*hi).
// 512 threads = 8 waves; wave w owns o in [w*16, w*16+16), all 64 n.
// U staged to LDS as bf16 hi/lo in B-fragment order -> ds_read_b128 at base+lane*16
// (conflict-free). A-frags from kB's global buffer (coalesced dwordx4, L2-hot).
// One barrier total. C/D layout: n = lane&15 (col), o = quad*4+reg (row).
__global__ __launch_bounds__(512) void kC1(const float* __restrict__ U,
                                           const unsigned short* __restrict__ afrag_hi,
                                           const unsigned short* __restrict__ afrag_lo,
                                           float* __restrict__ out,
                                           float* __restrict__ m_part,
                                           float* __restrict__ l_part) {
    __shared__ unsigned short Bh[8192];   // [kc][nt][quad][nlane][j] bf16 hi
    __shared__ unsigned short Bl[8192];   // same, lo
    const int tid = threadIdx.x;
    const int b = blockIdx.x;
    const int n0 = b * TILE_N;
    const int lane = tid & 63;
    const int w = tid >> 6;        // wave id 0..7 -> o base w*16
    const int quad = lane >> 4;    // 0..3
    const int nl = lane & 15;      // col lane

    // ---- stage U -> bf16 hi/lo fragments in LDS
#pragma unroll
    for (int r = 0; r < 4; ++r) {
        int idx = (r * 512 + tid) * 4;   // [0,8192)
        int n = idx >> 7;                // 0..63
        int k = idx & 127;               // multiple of 4
        int gn = n0 + n;
        float4 u4 = (gn < N_PTS) ? *(const float4*)&U[(size_t)gn * 128 + k]
                                 : make_float4(0, 0, 0, 0);
        unsigned short h0 = f2bf(u4.x), h1 = f2bf(u4.y), h2 = f2bf(u4.z), h3 = f2bf(u4.w);
        unsigned short l0 = f2bf(u4.x - bf2f(h0));
        unsigned short l1 = f2bf(u4.y - bf2f(h1));
        unsigned short l2 = f2bf(u4.z - bf2f(h2));
        unsigned short l3 = f2bf(u4.w - bf2f(h3));
        // dst (bf16 units): region (kc,nt), slot = quad*16+nlane, j = k&7 (0 or 4)
        int dst = ((k >> 5) * 4 + (n >> 4)) * 512 + (((k >> 3) & 3) * 16 + (n & 15)) * 8 + (k & 7);
        uint2 hp, lp;
        hp.x = (unsigned int)h0 | ((unsigned int)h1 << 16);
        hp.y = (unsigned int)h2 | ((unsigned int)h3 << 16);
        lp.x = (unsigned int)l0 | ((unsigned int)l1 << 16);
        lp.y = (unsigned int)l2 | ((unsigned int)l3 << 16);
        *(uint2*)&Bh[dst] = hp;
        *(uint2*)&Bl[dst] = lp;
    }

    // ---- A fragments (8 coalesced 16B loads per wave; same for all blocks -> L2)
    s16x8 Ah[4], Al[4];
#pragma unroll
    for (int kc = 0; kc < 4; ++kc) {
        size_t aoff = (size_t)(w * 4 + kc) * 512 + lane * 8;
        Ah[kc] = *(const s16x8*)(afrag_hi + aoff);
        Al[kc] = *(const s16x8*)(afrag_lo + aoff);
    }

    __syncthreads();   // the only barrier

    f32x4 acc[4];
#pragma unroll
    for (int nt = 0; nt < 4; ++nt) acc[nt] = (f32x4)(0.0f);

#pragma unroll
    for (int kc = 0; kc < 4; ++kc) {
#pragma unroll
        for (int nt = 0; nt < 4; ++nt) {
            int boff = ((kc * 4 + nt) * 512) + lane * 8;
            s16x8 bh = *(s16x8*)&Bh[boff];
            s16x8 bl = *(s16x8*)&Bl[boff];
            acc[nt] = __builtin_amdgcn_mfma_f32_16x16x32_bf16(Ah[kc], bh, acc[nt], 0, 0, 0);
            acc[nt] = __builtin_amdgcn_mfma_f32_16x16x32_bf16(Al[kc], bh, acc[nt], 0, 0, 0);
            acc[nt] = __builtin_amdgcn_mfma_f32_16x16x32_bf16(Ah[kc], bl, acc[nt], 0, 0, 0);
        }
    }

    // ---- OOB guard (lane covers n = n0 + nt*16 + nl)
#pragma unroll
    for (int nt = 0; nt < 4; ++nt) {
        if (n0 + nt * 16 + nl >= N_PTS) {
#pragma unroll
            for (int reg = 0; reg < 4; ++reg) acc[nt][reg] = -3.4e38f;
        }
    }

    // ---- per-o max over 64 n: in-register over nt, butterfly over 16-lane col group
    float mb[4];
#pragma unroll
    for (int reg = 0; reg < 4; ++reg)
        mb[reg] = fmaxf(fmaxf(acc[0][reg], acc[1][reg]), fmaxf(acc[2][reg], acc[3][reg]));
#pragma unroll
    for (int s = 1; s < 16; s <<= 1) {
#pragma unroll
        for (int reg = 0; reg < 4; ++reg) mb[reg] = fmaxf(mb[reg], __shfl_xor(mb[reg], s));
    }

    // ---- exp in place + store unnormalized
#pragma unroll
    for (int nt = 0; nt < 4; ++nt) {
#pragma unroll
        for (int reg = 0; reg < 4; ++reg) acc[nt][reg] = __expf(acc[nt][reg] - mb[reg]);
        int gn = n0 + nt * 16 + nl;
        if (gn < N_PTS)
            *(f32x4*)&out[(size_t)gn * 128 + w * 16 + quad * 4] = acc[nt];
    }

    // ---- per-o sum
    float ls[4];
#pragma unroll
    for (int reg = 0; reg < 4; ++reg)
        ls[reg] = ((acc[0][reg] + acc[1][reg]) + (acc[2][reg] + acc[3][reg]));
#pragma unroll
    for (int s = 1; s < 16; s <<= 1) {
#pragma unroll
        for (int reg = 0; reg < 4; ++reg) ls[reg] += __shfl_xor(ls[reg], s);
    }

    if (nl == 0) {
#pragma unroll
        for (int reg = 0; reg < 4; ++reg) {
            int o = w * 16 + quad * 4 + reg;
            m_part[(size_t)o * NB1 + b] = mb[reg];
            l_part[(size_t)o * NB1 + b] = ls[reg];
        }
    }
}

// ---------------- Kernel C2: combine (m,l) over blocks; [o][b] layout -> coalesced
__global__ __launch_bounds__(256) void kC2(const float* __restrict__ m_part,
                                           const float* __restrict__ l_part,
                                           float* __restrict__ scale) {
    const int o = blockIdx.x;
    const int tid = threadIdx.x;
    const float* __restrict__ mp = m_part + (size_t)o * NB1;
    const float* __restrict__ lp = l_part + (size_t)o * NB1;
    __shared__ float sm[256];
    float m = -3.4e38f;
    for (int b = tid; b < NB1; b += 256) m = fmaxf(m, mp[b]);
    sm[tid] = m;
    __syncthreads();
    for (int s = 128; s >= 1; s >>= 1) {
        if (tid < s) sm[tid] = fmaxf(sm[tid], sm[tid + s]);
        __syncthreads();
    }
    m = sm[0];
    __syncthreads();
    float l = 0.0f;
    for (int b = tid; b < NB1; b += 256)
        l += lp[b] * __expf(mp[b] - m);
    sm[tid] = l;
    __syncthreads();
    for (int s = 128; s >= 1; s >>= 1) {
        if (tid < s) sm[tid] += sm[tid + s];
        __syncthreads();
    }
    l = sm[0];
    float inv = 1.0f / l;
    for (int b = tid; b < NB1; b += 256)
        scale[(size_t)o * NB1 + b] = __expf(mp[b] - m) * inv;
}

// ---------------- Kernel C3: out[n][o] *= scale[o][n/64]
__global__ __launch_bounds__(256) void kC3(float* __restrict__ out,
                                           const float* __restrict__ scale) {
    const int b = blockIdx.x;
    const int tid = threadIdx.x;
    __shared__ float sc[128];
    if (tid < 128) sc[tid] = scale[(size_t)tid * NB1 + b];
    __syncthreads();
    const int n0 = b * TILE_N;
#pragma unroll
    for (int r = 0; r < 8; ++r) {
        int idx = (r * 256 + tid) * 4;   // [0,8192)
        int n = idx >> 7;
        int o = idx & 127;
        int gn = n0 + n;
        if (gn < N_PTS) {
            float4 v = *(float4*)&out[(size_t)gn * 128 + o];
            v.x *= sc[o];
            v.y *= sc[o + 1];
            v.z *= sc[o + 2];
            v.w *= sc[o + 3];
            *(float4*)&out[(size_t)gn * 128 + o] = v;
        }
    }
}

extern "C" void kernel_launch(void* const* d_in, const int* in_sizes, int n_in,
                              void* d_out, int out_size, void* d_ws, size_t ws_size,
                              hipStream_t stream) {
    const float* x = (const float*)d_in[0];       // (N, 128)
    const float* U = (const float*)d_in[1];       // (N, 128)
    const float* coeffs = (const float*)d_in[2];  // (128, 128, 128)
    float* out = (float*)d_out;                   // (N, 128)

    // workspace layout (float units; keep 16B alignment for frag buffers)
    float* f = (float*)d_ws;
    float* spec = f;                                    // 16384
    unsigned short* afrag_hi = (unsigned short*)(f + 16384);   // 16384 bf16 = 8192 f
    unsigned short* afrag_lo = (unsigned short*)(f + 16384 + 8192);
    float* m_part = f + 16384 + 16384;                  // 128*NB1 ([o][b])
    float* l_part = m_part + (size_t)128 * NB1;
    float* scale = l_part + (size_t)128 * NB1;          // 128*NB1
    float* partial2 = scale + (size_t)128 * NB1;        // 8*16384
    float* partialsA = partial2 + 8 * 16384;

    size_t fixed_bytes = ((size_t)(16384 * 2) + (size_t)NB1 * 128 * 3 + (size_t)8 * 16384) * 4;
    int nA = 512;
    if (ws_size > fixed_bytes) {
        size_t avail = (ws_size - fixed_bytes) / 65536;   // 64KB per partial
        if ((size_t)nA > avail) nA = (int)avail;
    } else {
        nA = 1;
    }
    if (nA < 1) nA = 1;
    int chunk = (N_PTS + nA - 1) / nA;

    kA<<<nA, 256, 0, stream>>>(U, x, partialsA, chunk);
    kA2a<<<512, 256, 0, stream>>>(partialsA, partial2, nA);
    kA2b<<<64, 256, 0, stream>>>(partial2, spec);
    kB<<<4096, 256, 0, stream>>>(coeffs, spec, afrag_hi, afrag_lo);
    kC1<<<NB1, 512, 0, stream>>>(U, afrag_hi, afrag_lo, out, m_part, l_part);
    kC2<<<128, 256, 0, stream>>>(m_part, l_part, scale);
    kC3<<<NB1, 256, 0, stream>>>(out, scale);
}

// Round 6
// 206.793 us; speedup vs baseline: 20.7233x; 1.1160x over previous
//
#include <hip/hip_runtime.h>
#include <math.h>

#define N_PTS 100000
#define KDIM 128
#define CDIM 128          // IN_C == OUT_C == 128
#define TILE_N 64
#define NB1 ((N_PTS + TILE_N - 1) / TILE_N)   // 1563 C1 blocks

typedef short s16x8 __attribute__((ext_vector_type(8)));
typedef float f32x4 __attribute__((ext_vector_type(4)));

// round-to-nearest-even float -> bf16 bits
static __device__ __forceinline__ unsigned short f2bf(float f) {
    unsigned int u = __float_as_uint(f);
    unsigned int r = (u + 0x7FFFu + ((u >> 16) & 1u)) >> 16;
    return (unsigned short)r;
}
static __device__ __forceinline__ float bf2f(unsigned short h) {
    return __uint_as_float(((unsigned int)h) << 16);
}

// truncation hi/lo split (cheap; residual error ~2^-16 relative)
static __device__ __forceinline__ void split_trunc(float v, unsigned short& hi, unsigned short& lo) {
    unsigned int u = __float_as_uint(v);
    unsigned int uh = u & 0xFFFF0000u;
    float lf = v - __uint_as_float(uh);
    hi = (unsigned short)(u >> 16);
    lo = (unsigned short)(__float_as_uint(lf) >> 16);
}

// fragment dst offset (u16 units) for element (local n = nloc in [0,32), channel c in [0,128))
// A-frag (U): m=c, k=nloc ; B-frag (x): n=c, k=nloc — same formula for both.
static __device__ __forceinline__ int frag_dst(int nloc, int c) {
    return (c >> 4) * 512 + (((nloc >> 3) & 3) * 16 + (c & 15)) * 8 + (nloc & 7);
}

// ---------------- Kernel A (MFMA): partials[b][k][i] = sum over block's n-chunk of U[n,k]*x[n,i]
// 256 thr = 4 waves. Per 32-n chunk: stage U (A-frag) and x (B-frag) as bf16 hi/lo,
// each wave computes 4mt x 4nt 16x16 tiles with 3-MFMA split. Epilogue: fp32 partials.
__global__ __launch_bounds__(256) void kA(const float* __restrict__ U,
                                          const float* __restrict__ x,
                                          float* __restrict__ partials,
                                          int chunk) {
    __shared__ unsigned short Ah_[4096], Al_[4096], Bh_[4096], Bl_[4096];   // 8 KB each
    const int tid = threadIdx.x;
    const int b = blockIdx.x;
    const int n_begin = b * chunk;
    const int n_end = min(N_PTS, n_begin + chunk);
    const int lane = tid & 63;
    const int w = tid >> 6;             // wave 0..3
    const int mtb = (w >> 1) * 4;       // k-tile base (0 or 4)
    const int ntb = (w & 1) * 4;        // i-tile base (0 or 4)
    const int quad = lane >> 4;
    const int nl = lane & 15;

    // staging role: thread owns channel c and quad q (rows q*8..q*8+7), 2 q's per thread
    const int sc = tid & 127;           // channel 0..127
    const int sqh = tid >> 7;           // 0..1 -> q = sqh*2 + p

    f32x4 acc[4][4];
#pragma unroll
    for (int mi = 0; mi < 4; ++mi)
#pragma unroll
        for (int ni = 0; ni < 4; ++ni) acc[mi][ni] = (f32x4)(0.0f);

    for (int n0 = n_begin; n0 < n_end; n0 += 32) {
        // ---- stage U and x: 8 rows per (c,q), truncation-split, one b128 write per frag half
#pragma unroll
        for (int p = 0; p < 2; ++p) {
            const int q = sqh * 2 + p;
            const int nb = q * 8;
            float uv[8], xv[8];
#pragma unroll
            for (int jj = 0; jj < 8; ++jj) {
                int gn = n0 + nb + jj;
                bool ok = (gn < n_end);
                uv[jj] = ok ? U[(size_t)gn * 128 + sc] : 0.0f;
                xv[jj] = ok ? x[(size_t)gn * 128 + sc] : 0.0f;
            }
            s16x8 uh, ul, xh, xl;
#pragma unroll
            for (int jj = 0; jj < 8; ++jj) {
                unsigned short h, l;
                split_trunc(uv[jj], h, l);
                uh[jj] = (short)h; ul[jj] = (short)l;
                split_trunc(xv[jj], h, l);
                xh[jj] = (short)h; xl[jj] = (short)l;
            }
            int dst = frag_dst(nb, sc);   // j-run of 8 consecutive u16, 16B aligned
            *(s16x8*)&Ah_[dst] = uh;
            *(s16x8*)&Al_[dst] = ul;
            *(s16x8*)&Bh_[dst] = xh;
            *(s16x8*)&Bl_[dst] = xl;
        }
        __syncthreads();

        // ---- compute: 16 tiles/wave, 3-MFMA split each
        s16x8 ah[4], al[4];
#pragma unroll
        for (int mi = 0; mi < 4; ++mi) {
            ah[mi] = *(s16x8*)&Ah_[(mtb + mi) * 512 + lane * 8];
            al[mi] = *(s16x8*)&Al_[(mtb + mi) * 512 + lane * 8];
        }
#pragma unroll
        for (int ni = 0; ni < 4; ++ni) {
            s16x8 bh = *(s16x8*)&Bh_[(ntb + ni) * 512 + lane * 8];
            s16x8 bl = *(s16x8*)&Bl_[(ntb + ni) * 512 + lane * 8];
#pragma unroll
            for (int mi = 0; mi < 4; ++mi) {
                acc[mi][ni] = __builtin_amdgcn_mfma_f32_16x16x32_bf16(ah[mi], bh, acc[mi][ni], 0, 0, 0);
                acc[mi][ni] = __builtin_amdgcn_mfma_f32_16x16x32_bf16(al[mi], bh, acc[mi][ni], 0, 0, 0);
                acc[mi][ni] = __builtin_amdgcn_mfma_f32_16x16x32_bf16(ah[mi], bl, acc[mi][ni], 0, 0, 0);
            }
        }
        __syncthreads();
    }

    // ---- epilogue: partials[b][k][i]; C/D layout: col(i)=nl, row(k)=quad*4+reg
    float* p = partials + (size_t)b * 16384;
#pragma unroll
    for (int mi = 0; mi < 4; ++mi) {
#pragma unroll
        for (int reg = 0; reg < 4; ++reg) {
            int k = (mtb + mi) * 16 + quad * 4 + reg;
#pragma unroll
            for (int ni = 0; ni < 4; ++ni) {
                int i = (ntb + ni) * 16 + nl;
                p[k * 128 + i] = acc[mi][ni][reg];
            }
        }
    }
}

// ---------------- Kernel A2a: partial2[s][j] = sum of partials[b][j] over this s-slice of b
__global__ __launch_bounds__(256) void kA2a(const float* __restrict__ partials,
                                            float* __restrict__ partial2, int nA) {
    const int jc = blockIdx.x >> 3;
    const int s = blockIdx.x & 7;
    const int j = jc * 256 + threadIdx.x;
    const int per = (nA + 7) >> 3;
    int b = s * per;
    const int be = min(b + per, nA);
    float a0 = 0.0f, a1 = 0.0f, a2 = 0.0f, a3 = 0.0f;
    for (; b + 4 <= be; b += 4) {
        a0 += partials[(size_t)(b + 0) * 16384 + j];
        a1 += partials[(size_t)(b + 1) * 16384 + j];
        a2 += partials[(size_t)(b + 2) * 16384 + j];
        a3 += partials[(size_t)(b + 3) * 16384 + j];
    }
    for (; b < be; ++b) a0 += partials[(size_t)b * 16384 + j];
    partial2[(size_t)s * 16384 + j] = (a0 + a1) + (a2 + a3);
}

// ---------------- Kernel A2b: spec[j] = sum_s partial2[s][j]
__global__ __launch_bounds__(256) void kA2b(const float* __restrict__ partial2,
                                            float* __restrict__ spec) {
    int j = blockIdx.x * 256 + threadIdx.x;
    float v0 = partial2[j];
    float v1 = partial2[16384 + j];
    float v2 = partial2[2 * 16384 + j];
    float v3 = partial2[3 * 16384 + j];
    float v4 = partial2[4 * 16384 + j];
    float v5 = partial2[5 * 16384 + j];
    float v6 = partial2[6 * 16384 + j];
    float v7 = partial2[7 * 16384 + j];
    spec[j] = ((v0 + v1) + (v2 + v3)) + ((v4 + v5) + (v6 + v7));
}

// ---------------- Kernel B: mixed[o][k] = sum_i coeffs[o][k][i]*spec[k][i]; one wave per (o,k).
// Emits bf16 hi/lo of mixed in A-FRAGMENT order for kC1.
__global__ __launch_bounds__(256) void kB(const float* __restrict__ coeffs,
                                          const float* __restrict__ spec,
                                          unsigned short* __restrict__ afrag_hi,
                                          unsigned short* __restrict__ afrag_lo) {
    int wave = (blockIdx.x * 256 + threadIdx.x) >> 6;   // [0, 16384)
    int lane = threadIdx.x & 63;
    int o = wave >> 7;
    int k = wave & 127;
    float2 c2 = *(const float2*)&coeffs[((size_t)o * 128 + k) * 128 + lane * 2];
    float2 s2 = *(const float2*)&spec[k * 128 + lane * 2];
    float v = c2.x * s2.x + c2.y * s2.y;
#pragma unroll
    for (int s = 32; s >= 1; s >>= 1) v += __shfl_xor(v, s);
    if (lane == 0) {
        unsigned short hi = f2bf(v);
        unsigned short lo = f2bf(v - bf2f(hi));
        int idx = ((o >> 4) * 4 + (k >> 5)) * 512 + (((k >> 3) & 3) * 16 + (o & 15)) * 8 + (k & 7);
        afrag_hi[idx] = hi;
        afrag_lo[idx] = lo;
    }
}

// ---------------- Kernel C1 (MFMA): 64n x 128o tile via bf16x2 split (hi*hi + hi*lo + lo*hi).
// 512 threads = 8 waves; wave w owns o in [w*16, w*16+16), all 64 n.
__global__ __launch_bounds__(512) void kC1(const float* __restrict__ U,
                                           const unsigned short* __restrict__ afrag_hi,
                                           const unsigned short* __restrict__ afrag_lo,
                                           float* __restrict__ out,
                                           float* __restrict__ m_part,
                                           float* __restrict__ l_part) {
    __shared__ unsigned short Bh[8192];   // [kc][nt][quad][nlane][j] bf16 hi
    __shared__ unsigned short Bl[8192];   // same, lo
    const int tid = threadIdx.x;
    const int b = blockIdx.x;
    const int n0 = b * TILE_N;
    const int lane = tid & 63;
    const int w = tid >> 6;        // wave id 0..7 -> o base w*16
    const int quad = lane >> 4;    // 0..3
    const int nl = lane & 15;      // col lane

    // ---- stage U -> bf16 hi/lo fragments in LDS
#pragma unroll
    for (int r = 0; r < 4; ++r) {
        int idx = (r * 512 + tid) * 4;   // [0,8192)
        int n = idx >> 7;                // 0..63
        int k = idx & 127;               // multiple of 4
        int gn = n0 + n;
        float4 u4 = (gn < N_PTS) ? *(const float4*)&U[(size_t)gn * 128 + k]
                                 : make_float4(0, 0, 0, 0);
        unsigned short h0 = f2bf(u4.x), h1 = f2bf(u4.y), h2 = f2bf(u4.z), h3 = f2bf(u4.w);
        unsigned short l0 = f2bf(u4.x - bf2f(h0));
        unsigned short l1 = f2bf(u4.y - bf2f(h1));
        unsigned short l2 = f2bf(u4.z - bf2f(h2));
        unsigned short l3 = f2bf(u4.w - bf2f(h3));
        int dst = ((k >> 5) * 4 + (n >> 4)) * 512 + (((k >> 3) & 3) * 16 + (n & 15)) * 8 + (k & 7);
        uint2 hp, lp;
        hp.x = (unsigned int)h0 | ((unsigned int)h1 << 16);
        hp.y = (unsigned int)h2 | ((unsigned int)h3 << 16);
        lp.x = (unsigned int)l0 | ((unsigned int)l1 << 16);
        lp.y = (unsigned int)l2 | ((unsigned int)l3 << 16);
        *(uint2*)&Bh[dst] = hp;
        *(uint2*)&Bl[dst] = lp;
    }

    // ---- A fragments (8 coalesced 16B loads per wave; same for all blocks -> L2)
    s16x8 Ah[4], Al[4];
#pragma unroll
    for (int kc = 0; kc < 4; ++kc) {
        size_t aoff = (size_t)(w * 4 + kc) * 512 + lane * 8;
        Ah[kc] = *(const s16x8*)(afrag_hi + aoff);
        Al[kc] = *(const s16x8*)(afrag_lo + aoff);
    }

    __syncthreads();   // the only barrier

    f32x4 acc[4];
#pragma unroll
    for (int nt = 0; nt < 4; ++nt) acc[nt] = (f32x4)(0.0f);

#pragma unroll
    for (int kc = 0; kc < 4; ++kc) {
#pragma unroll
        for (int nt = 0; nt < 4; ++nt) {
            int boff = ((kc * 4 + nt) * 512) + lane * 8;
            s16x8 bh = *(s16x8*)&Bh[boff];
            s16x8 bl = *(s16x8*)&Bl[boff];
            acc[nt] = __builtin_amdgcn_mfma_f32_16x16x32_bf16(Ah[kc], bh, acc[nt], 0, 0, 0);
            acc[nt] = __builtin_amdgcn_mfma_f32_16x16x32_bf16(Al[kc], bh, acc[nt], 0, 0, 0);
            acc[nt] = __builtin_amdgcn_mfma_f32_16x16x32_bf16(Ah[kc], bl, acc[nt], 0, 0, 0);
        }
    }

    // ---- OOB guard (lane covers n = n0 + nt*16 + nl)
#pragma unroll
    for (int nt = 0; nt < 4; ++nt) {
        if (n0 + nt * 16 + nl >= N_PTS) {
#pragma unroll
            for (int reg = 0; reg < 4; ++reg) acc[nt][reg] = -3.4e38f;
        }
    }

    // ---- per-o max over 64 n
    float mb[4];
#pragma unroll
    for (int reg = 0; reg < 4; ++reg)
        mb[reg] = fmaxf(fmaxf(acc[0][reg], acc[1][reg]), fmaxf(acc[2][reg], acc[3][reg]));
#pragma unroll
    for (int s = 1; s < 16; s <<= 1) {
#pragma unroll
        for (int reg = 0; reg < 4; ++reg) mb[reg] = fmaxf(mb[reg], __shfl_xor(mb[reg], s));
    }

    // ---- exp in place + store unnormalized
#pragma unroll
    for (int nt = 0; nt < 4; ++nt) {
#pragma unroll
        for (int reg = 0; reg < 4; ++reg) acc[nt][reg] = __expf(acc[nt][reg] - mb[reg]);
        int gn = n0 + nt * 16 + nl;
        if (gn < N_PTS)
            *(f32x4*)&out[(size_t)gn * 128 + w * 16 + quad * 4] = acc[nt];
    }

    // ---- per-o sum
    float ls[4];
#pragma unroll
    for (int reg = 0; reg < 4; ++reg)
        ls[reg] = ((acc[0][reg] + acc[1][reg]) + (acc[2][reg] + acc[3][reg]));
#pragma unroll
    for (int s = 1; s < 16; s <<= 1) {
#pragma unroll
        for (int reg = 0; reg < 4; ++reg) ls[reg] += __shfl_xor(ls[reg], s);
    }

    if (nl == 0) {
#pragma unroll
        for (int reg = 0; reg < 4; ++reg) {
            int o = w * 16 + quad * 4 + reg;
            m_part[(size_t)o * NB1 + b] = mb[reg];
            l_part[(size_t)o * NB1 + b] = ls[reg];
        }
    }
}

// ---------------- Kernel C2: combine (m,l) over blocks; [o][b] layout -> coalesced
__global__ __launch_bounds__(256) void kC2(const float* __restrict__ m_part,
                                           const float* __restrict__ l_part,
                                           float* __restrict__ scale) {
    const int o = blockIdx.x;
    const int tid = threadIdx.x;
    const float* __restrict__ mp = m_part + (size_t)o * NB1;
    const float* __restrict__ lp = l_part + (size_t)o * NB1;
    __shared__ float sm[256];
    float m = -3.4e38f;
    for (int b = tid; b < NB1; b += 256) m = fmaxf(m, mp[b]);
    sm[tid] = m;
    __syncthreads();
    for (int s = 128; s >= 1; s >>= 1) {
        if (tid < s) sm[tid] = fmaxf(sm[tid], sm[tid + s]);
        __syncthreads();
    }
    m = sm[0];
    __syncthreads();
    float l = 0.0f;
    for (int b = tid; b < NB1; b += 256)
        l += lp[b] * __expf(mp[b] - m);
    sm[tid] = l;
    __syncthreads();
    for (int s = 128; s >= 1; s >>= 1) {
        if (tid < s) sm[tid] += sm[tid + s];
        __syncthreads();
    }
    l = sm[0];
    float inv = 1.0f / l;
    for (int b = tid; b < NB1; b += 256)
        scale[(size_t)o * NB1 + b] = __expf(mp[b] - m) * inv;
}

// ---------------- Kernel C3: out[n][o] *= scale[o][n/64]
__global__ __launch_bounds__(256) void kC3(float* __restrict__ out,
                                           const float* __restrict__ scale) {
    const int b = blockIdx.x;
    const int tid = threadIdx.x;
    __shared__ float sc[128];
    if (tid < 128) sc[tid] = scale[(size_t)tid * NB1 + b];
    __syncthreads();
    const int n0 = b * TILE_N;
#pragma unroll
    for (int r = 0; r < 8; ++r) {
        int idx = (r * 256 + tid) * 4;   // [0,8192)
        int n = idx >> 7;
        int o = idx & 127;
        int gn = n0 + n;
        if (gn < N_PTS) {
            float4 v = *(float4*)&out[(size_t)gn * 128 + o];
            v.x *= sc[o];
            v.y *= sc[o + 1];
            v.z *= sc[o + 2];
            v.w *= sc[o + 3];
            *(float4*)&out[(size_t)gn * 128 + o] = v;
        }
    }
}

extern "C" void kernel_launch(void* const* d_in, const int* in_sizes, int n_in,
                              void* d_out, int out_size, void* d_ws, size_t ws_size,
                              hipStream_t stream) {
    const float* x = (const float*)d_in[0];       // (N, 128)
    const float* U = (const float*)d_in[1];       // (N, 128)
    const float* coeffs = (const float*)d_in[2];  // (128, 128, 128)
    float* out = (float*)d_out;                   // (N, 128)

    // workspace layout (float units; keep 16B alignment for frag buffers)
    float* f = (float*)d_ws;
    float* spec = f;                                    // 16384
    unsigned short* afrag_hi = (unsigned short*)(f + 16384);   // 16384 bf16 = 8192 f
    unsigned short* afrag_lo = (unsigned short*)(f + 16384 + 8192);
    float* m_part = f + 16384 + 16384;                  // 128*NB1 ([o][b])
    float* l_part = m_part + (size_t)128 * NB1;
    float* scale = l_part + (size_t)128 * NB1;          // 128*NB1
    float* partial2 = scale + (size_t)128 * NB1;        // 8*16384
    float* partialsA = partial2 + 8 * 16384;

    size_t fixed_bytes = ((size_t)(16384 * 2) + (size_t)NB1 * 128 * 3 + (size_t)8 * 16384) * 4;
    int nA = 512;
    if (ws_size > fixed_bytes) {
        size_t avail = (ws_size - fixed_bytes) / 65536;   // 64KB per partial
        if ((size_t)nA > avail) nA = (int)avail;
    } else {
        nA = 1;
    }
    if (nA < 1) nA = 1;
    int chunk = (N_PTS + nA - 1) / nA;

    kA<<<nA, 256, 0, stream>>>(U, x, partialsA, chunk);
    kA2a<<<512, 256, 0, stream>>>(partialsA, partial2, nA);
    kA2b<<<64, 256, 0, stream>>>(partial2, spec);
    kB<<<4096, 256, 0, stream>>>(coeffs, spec, afrag_hi, afrag_lo);
    kC1<<<NB1, 512, 0, stream>>>(U, afrag_hi, afrag_lo, out, m_part, l_part);
    kC2<<<128, 256, 0, stream>>>(m_part, l_part, scale);
    kC3<<<NB1, 256, 0, stream>>>(out, scale);
}

// Round 7
// 206.536 us; speedup vs baseline: 20.7491x; 1.0012x over previous
//
#include <hip/hip_runtime.h>
#include <math.h>

#define N_PTS 100000
#define KDIM 128
#define CDIM 128          // IN_C == OUT_C == 128
#define TILE_N 64
#define NB1 ((N_PTS + TILE_N - 1) / TILE_N)   // 1563 C1 blocks

typedef short s16x8 __attribute__((ext_vector_type(8)));
typedef float f32x4 __attribute__((ext_vector_type(4)));

// round-to-nearest-even float -> bf16 bits
static __device__ __forceinline__ unsigned short f2bf(float f) {
    unsigned int u = __float_as_uint(f);
    unsigned int r = (u + 0x7FFFu + ((u >> 16) & 1u)) >> 16;
    return (unsigned short)r;
}
static __device__ __forceinline__ float bf2f(unsigned short h) {
    return __uint_as_float(((unsigned int)h) << 16);
}

// truncation hi/lo split (cheap; residual error ~2^-16 relative)
static __device__ __forceinline__ void split_trunc(float v, unsigned short& hi, unsigned short& lo) {
    unsigned int u = __float_as_uint(v);
    unsigned int uh = u & 0xFFFF0000u;
    float lf = v - __uint_as_float(uh);
    hi = (unsigned short)(u >> 16);
    lo = (unsigned short)(__float_as_uint(lf) >> 16);
}

// fragment dst offset (u16 units) for element (local n = nloc in [0,32), channel c in [0,128))
static __device__ __forceinline__ int frag_dst(int nloc, int c) {
    return (c >> 4) * 512 + (((nloc >> 3) & 3) * 16 + (c & 15)) * 8 + (nloc & 7);
}

// ---------------- Kernel A (MFMA v2): partials[b][k][i] = sum over block's n-chunk of U[n,k]*x[n,i]
// 512 thr = 8 waves; wave w owns mt in {(w&3)*2, +1}, nt in {(w>>2)*4 .. +3}.
// 64-n chunks: 2 MFMA K=32 subchunks per chunk, one barrier pair per 64 n.
// LDS 64 KB -> 2 blocks/CU (grid-limited anyway); 16 waves/CU.
__global__ __launch_bounds__(512, 4) void kA(const float* __restrict__ U,
                                             const float* __restrict__ x,
                                             float* __restrict__ partials,
                                             int chunk) {
    __shared__ unsigned short Ah_[8192], Al_[8192], Bh_[8192], Bl_[8192];   // 16 KB each
    const int tid = threadIdx.x;
    const int b = blockIdx.x;
    const int n_begin = b * chunk;
    const int n_end = min(N_PTS, n_begin + chunk);
    const int lane = tid & 63;
    const int w = tid >> 6;             // wave 0..7
    const int mtb = (w & 3) * 2;        // k-tile base: 2 tiles
    const int ntb = (w >> 2) * 4;       // i-tile base: 4 tiles
    const int quad = lane >> 4;
    const int nl = lane & 15;

    // staging role: thread owns channel sc, row-run rq (rows rq*16 + p*8 + jj within the 64-n chunk)
    const int sc = tid & 127;           // channel 0..127
    const int rq = tid >> 7;            // 0..3

    f32x4 acc[2][4];
#pragma unroll
    for (int mi = 0; mi < 2; ++mi)
#pragma unroll
        for (int ni = 0; ni < 4; ++ni) acc[mi][ni] = (f32x4)(0.0f);

    for (int n0 = n_begin; n0 < n_end; n0 += 64) {
        // ---- stage 64 rows of U (A-frag) and x (B-frag), bf16 hi/lo
#pragma unroll
        for (int p = 0; p < 2; ++p) {
            const int nb = rq * 16 + p * 8;      // row base within chunk, multiple of 8
            float uv[8], xv[8];
#pragma unroll
            for (int jj = 0; jj < 8; ++jj) {
                int gn = n0 + nb + jj;
                bool ok = (gn < n_end);
                uv[jj] = ok ? U[(size_t)gn * 128 + sc] : 0.0f;
                xv[jj] = ok ? x[(size_t)gn * 128 + sc] : 0.0f;
            }
            s16x8 uh, ul, xh, xl;
#pragma unroll
            for (int jj = 0; jj < 8; ++jj) {
                unsigned short h, l;
                split_trunc(uv[jj], h, l);
                uh[jj] = (short)h; ul[jj] = (short)l;
                split_trunc(xv[jj], h, l);
                xh[jj] = (short)h; xl[jj] = (short)l;
            }
            const int sub = nb >> 5;             // 0..1
            const int dst = sub * 4096 + frag_dst(nb & 31, sc);
            *(s16x8*)&Ah_[dst] = uh;
            *(s16x8*)&Al_[dst] = ul;
            *(s16x8*)&Bh_[dst] = xh;
            *(s16x8*)&Bl_[dst] = xl;
        }
        __syncthreads();

        // ---- compute: 2 subchunks x 8 tiles/wave x 3-MFMA split
#pragma unroll
        for (int sub = 0; sub < 2; ++sub) {
            const int base = sub * 4096;
            s16x8 ah[2], al[2];
#pragma unroll
            for (int mi = 0; mi < 2; ++mi) {
                ah[mi] = *(s16x8*)&Ah_[base + (mtb + mi) * 512 + lane * 8];
                al[mi] = *(s16x8*)&Al_[base + (mtb + mi) * 512 + lane * 8];
            }
#pragma unroll
            for (int ni = 0; ni < 4; ++ni) {
                s16x8 bh = *(s16x8*)&Bh_[base + (ntb + ni) * 512 + lane * 8];
                s16x8 bl = *(s16x8*)&Bl_[base + (ntb + ni) * 512 + lane * 8];
#pragma unroll
                for (int mi = 0; mi < 2; ++mi) {
                    acc[mi][ni] = __builtin_amdgcn_mfma_f32_16x16x32_bf16(ah[mi], bh, acc[mi][ni], 0, 0, 0);
                    acc[mi][ni] = __builtin_amdgcn_mfma_f32_16x16x32_bf16(al[mi], bh, acc[mi][ni], 0, 0, 0);
                    acc[mi][ni] = __builtin_amdgcn_mfma_f32_16x16x32_bf16(ah[mi], bl, acc[mi][ni], 0, 0, 0);
                }
            }
        }
        __syncthreads();
    }

    // ---- epilogue: partials[b][k][i]; C/D layout: col(i)=nl, row(k)=quad*4+reg
    float* p = partials + (size_t)b * 16384;
#pragma unroll
    for (int mi = 0; mi < 2; ++mi) {
#pragma unroll
        for (int reg = 0; reg < 4; ++reg) {
            int k = (mtb + mi) * 16 + quad * 4 + reg;
#pragma unroll
            for (int ni = 0; ni < 4; ++ni) {
                int i = (ntb + ni) * 16 + nl;
                p[k * 128 + i] = acc[mi][ni][reg];
            }
        }
    }
}

// ---------------- Kernel A2a: partial2[s][j] = sum of partials[b][j] over this s-slice of b
__global__ __launch_bounds__(256) void kA2a(const float* __restrict__ partials,
                                            float* __restrict__ partial2, int nA) {
    const int jc = blockIdx.x >> 3;
    const int s = blockIdx.x & 7;
    const int j = jc * 256 + threadIdx.x;
    const int per = (nA + 7) >> 3;
    int b = s * per;
    const int be = min(b + per, nA);
    float a0 = 0.0f, a1 = 0.0f, a2 = 0.0f, a3 = 0.0f;
    for (; b + 4 <= be; b += 4) {
        a0 += partials[(size_t)(b + 0) * 16384 + j];
        a1 += partials[(size_t)(b + 1) * 16384 + j];
        a2 += partials[(size_t)(b + 2) * 16384 + j];
        a3 += partials[(size_t)(b + 3) * 16384 + j];
    }
    for (; b < be; ++b) a0 += partials[(size_t)b * 16384 + j];
    partial2[(size_t)s * 16384 + j] = (a0 + a1) + (a2 + a3);
}

// ---------------- Kernel A2b: spec[j] = sum_s partial2[s][j]
__global__ __launch_bounds__(256) void kA2b(const float* __restrict__ partial2,
                                            float* __restrict__ spec) {
    int j = blockIdx.x * 256 + threadIdx.x;
    float v0 = partial2[j];
    float v1 = partial2[16384 + j];
    float v2 = partial2[2 * 16384 + j];
    float v3 = partial2[3 * 16384 + j];
    float v4 = partial2[4 * 16384 + j];
    float v5 = partial2[5 * 16384 + j];
    float v6 = partial2[6 * 16384 + j];
    float v7 = partial2[7 * 16384 + j];
    spec[j] = ((v0 + v1) + (v2 + v3)) + ((v4 + v5) + (v6 + v7));
}

// ---------------- Kernel B: mixed[o][k] = sum_i coeffs[o][k][i]*spec[k][i]; one wave per (o,k).
// Emits bf16 hi/lo of mixed in A-FRAGMENT order for kC1.
__global__ __launch_bounds__(256) void kB(const float* __restrict__ coeffs,
                                          const float* __restrict__ spec,
                                          unsigned short* __restrict__ afrag_hi,
                                          unsigned short* __restrict__ afrag_lo) {
    int wave = (blockIdx.x * 256 + threadIdx.x) >> 6;   // [0, 16384)
    int lane = threadIdx.x & 63;
    int o = wave >> 7;
    int k = wave & 127;
    float2 c2 = *(const float2*)&coeffs[((size_t)o * 128 + k) * 128 + lane * 2];
    float2 s2 = *(const float2*)&spec[k * 128 + lane * 2];
    float v = c2.x * s2.x + c2.y * s2.y;
#pragma unroll
    for (int s = 32; s >= 1; s >>= 1) v += __shfl_xor(v, s);
    if (lane == 0) {
        unsigned short hi = f2bf(v);
        unsigned short lo = f2bf(v - bf2f(hi));
        int idx = ((o >> 4) * 4 + (k >> 5)) * 512 + (((k >> 3) & 3) * 16 + (o & 15)) * 8 + (k & 7);
        afrag_hi[idx] = hi;
        afrag_lo[idx] = lo;
    }
}

// ---------------- Kernel C1 (MFMA): 64n x 128o tile via bf16x2 split (hi*hi + hi*lo + lo*hi).
// 512 threads = 8 waves; wave w owns o in [w*16, w*16+16), all 64 n.
__global__ __launch_bounds__(512) void kC1(const float* __restrict__ U,
                                           const unsigned short* __restrict__ afrag_hi,
                                           const unsigned short* __restrict__ afrag_lo,
                                           float* __restrict__ out,
                                           float* __restrict__ m_part,
                                           float* __restrict__ l_part) {
    __shared__ unsigned short Bh[8192];   // [kc][nt][quad][nlane][j] bf16 hi
    __shared__ unsigned short Bl[8192];   // same, lo
    const int tid = threadIdx.x;
    const int b = blockIdx.x;
    const int n0 = b * TILE_N;
    const int lane = tid & 63;
    const int w = tid >> 6;        // wave id 0..7 -> o base w*16
    const int quad = lane >> 4;    // 0..3
    const int nl = lane & 15;      // col lane

    // ---- stage U -> bf16 hi/lo fragments in LDS
#pragma unroll
    for (int r = 0; r < 4; ++r) {
        int idx = (r * 512 + tid) * 4;   // [0,8192)
        int n = idx >> 7;                // 0..63
        int k = idx & 127;               // multiple of 4
        int gn = n0 + n;
        float4 u4 = (gn < N_PTS) ? *(const float4*)&U[(size_t)gn * 128 + k]
                                 : make_float4(0, 0, 0, 0);
        unsigned short h0 = f2bf(u4.x), h1 = f2bf(u4.y), h2 = f2bf(u4.z), h3 = f2bf(u4.w);
        unsigned short l0 = f2bf(u4.x - bf2f(h0));
        unsigned short l1 = f2bf(u4.y - bf2f(h1));
        unsigned short l2 = f2bf(u4.z - bf2f(h2));
        unsigned short l3 = f2bf(u4.w - bf2f(h3));
        int dst = ((k >> 5) * 4 + (n >> 4)) * 512 + (((k >> 3) & 3) * 16 + (n & 15)) * 8 + (k & 7);
        uint2 hp, lp;
        hp.x = (unsigned int)h0 | ((unsigned int)h1 << 16);
        hp.y = (unsigned int)h2 | ((unsigned int)h3 << 16);
        lp.x = (unsigned int)l0 | ((unsigned int)l1 << 16);
        lp.y = (unsigned int)l2 | ((unsigned int)l3 << 16);
        *(uint2*)&Bh[dst] = hp;
        *(uint2*)&Bl[dst] = lp;
    }

    // ---- A fragments (8 coalesced 16B loads per wave; same for all blocks -> L2)
    s16x8 Ah[4], Al[4];
#pragma unroll
    for (int kc = 0; kc < 4; ++kc) {
        size_t aoff = (size_t)(w * 4 + kc) * 512 + lane * 8;
        Ah[kc] = *(const s16x8*)(afrag_hi + aoff);
        Al[kc] = *(const s16x8*)(afrag_lo + aoff);
    }

    __syncthreads();   // the only barrier

    f32x4 acc[4];
#pragma unroll
    for (int nt = 0; nt < 4; ++nt) acc[nt] = (f32x4)(0.0f);

#pragma unroll
    for (int kc = 0; kc < 4; ++kc) {
#pragma unroll
        for (int nt = 0; nt < 4; ++nt) {
            int boff = ((kc * 4 + nt) * 512) + lane * 8;
            s16x8 bh = *(s16x8*)&Bh[boff];
            s16x8 bl = *(s16x8*)&Bl[boff];
            acc[nt] = __builtin_amdgcn_mfma_f32_16x16x32_bf16(Ah[kc], bh, acc[nt], 0, 0, 0);
            acc[nt] = __builtin_amdgcn_mfma_f32_16x16x32_bf16(Al[kc], bh, acc[nt], 0, 0, 0);
            acc[nt] = __builtin_amdgcn_mfma_f32_16x16x32_bf16(Ah[kc], bl, acc[nt], 0, 0, 0);
        }
    }

    // ---- OOB guard (lane covers n = n0 + nt*16 + nl)
#pragma unroll
    for (int nt = 0; nt < 4; ++nt) {
        if (n0 + nt * 16 + nl >= N_PTS) {
#pragma unroll
            for (int reg = 0; reg < 4; ++reg) acc[nt][reg] = -3.4e38f;
        }
    }

    // ---- per-o max over 64 n
    float mb[4];
#pragma unroll
    for (int reg = 0; reg < 4; ++reg)
        mb[reg] = fmaxf(fmaxf(acc[0][reg], acc[1][reg]), fmaxf(acc[2][reg], acc[3][reg]));
#pragma unroll
    for (int s = 1; s < 16; s <<= 1) {
#pragma unroll
        for (int reg = 0; reg < 4; ++reg) mb[reg] = fmaxf(mb[reg], __shfl_xor(mb[reg], s));
    }

    // ---- exp in place + store unnormalized
#pragma unroll
    for (int nt = 0; nt < 4; ++nt) {
#pragma unroll
        for (int reg = 0; reg < 4; ++reg) acc[nt][reg] = __expf(acc[nt][reg] - mb[reg]);
        int gn = n0 + nt * 16 + nl;
        if (gn < N_PTS)
            *(f32x4*)&out[(size_t)gn * 128 + w * 16 + quad * 4] = acc[nt];
    }

    // ---- per-o sum
    float ls[4];
#pragma unroll
    for (int reg = 0; reg < 4; ++reg)
        ls[reg] = ((acc[0][reg] + acc[1][reg]) + (acc[2][reg] + acc[3][reg]));
#pragma unroll
    for (int s = 1; s < 16; s <<= 1) {
#pragma unroll
        for (int reg = 0; reg < 4; ++reg) ls[reg] += __shfl_xor(ls[reg], s);
    }

    if (nl == 0) {
#pragma unroll
        for (int reg = 0; reg < 4; ++reg) {
            int o = w * 16 + quad * 4 + reg;
            m_part[(size_t)o * NB1 + b] = mb[reg];
            l_part[(size_t)o * NB1 + b] = ls[reg];
        }
    }
}

// ---------------- Kernel C2: combine (m,l) over blocks; [o][b] layout -> coalesced
__global__ __launch_bounds__(256) void kC2(const float* __restrict__ m_part,
                                           const float* __restrict__ l_part,
                                           float* __restrict__ scale) {
    const int o = blockIdx.x;
    const int tid = threadIdx.x;
    const float* __restrict__ mp = m_part + (size_t)o * NB1;
    const float* __restrict__ lp = l_part + (size_t)o * NB1;
    __shared__ float sm[256];
    float m = -3.4e38f;
    for (int b = tid; b < NB1; b += 256) m = fmaxf(m, mp[b]);
    sm[tid] = m;
    __syncthreads();
    for (int s = 128; s >= 1; s >>= 1) {
        if (tid < s) sm[tid] = fmaxf(sm[tid], sm[tid + s]);
        __syncthreads();
    }
    m = sm[0];
    __syncthreads();
    float l = 0.0f;
    for (int b = tid; b < NB1; b += 256)
        l += lp[b] * __expf(mp[b] - m);
    sm[tid] = l;
    __syncthreads();
    for (int s = 128; s >= 1; s >>= 1) {
        if (tid < s) sm[tid] += sm[tid + s];
        __syncthreads();
    }
    l = sm[0];
    float inv = 1.0f / l;
    for (int b = tid; b < NB1; b += 256)
        scale[(size_t)o * NB1 + b] = __expf(mp[b] - m) * inv;
}

// ---------------- Kernel C3: out[n][o] *= scale[o][n/64]
__global__ __launch_bounds__(256) void kC3(float* __restrict__ out,
                                           const float* __restrict__ scale) {
    const int b = blockIdx.x;
    const int tid = threadIdx.x;
    __shared__ float sc[128];
    if (tid < 128) sc[tid] = scale[(size_t)tid * NB1 + b];
    __syncthreads();
    const int n0 = b * TILE_N;
#pragma unroll
    for (int r = 0; r < 8; ++r) {
        int idx = (r * 256 + tid) * 4;   // [0,8192)
        int n = idx >> 7;
        int o = idx & 127;
        int gn = n0 + n;
        if (gn < N_PTS) {
            float4 v = *(float4*)&out[(size_t)gn * 128 + o];
            v.x *= sc[o];
            v.y *= sc[o + 1];
            v.z *= sc[o + 2];
            v.w *= sc[o + 3];
            *(float4*)&out[(size_t)gn * 128 + o] = v;
        }
    }
}

extern "C" void kernel_launch(void* const* d_in, const int* in_sizes, int n_in,
                              void* d_out, int out_size, void* d_ws, size_t ws_size,
                              hipStream_t stream) {
    const float* x = (const float*)d_in[0];       // (N, 128)
    const float* U = (const float*)d_in[1];       // (N, 128)
    const float* coeffs = (const float*)d_in[2];  // (128, 128, 128)
    float* out = (float*)d_out;                   // (N, 128)

    // workspace layout (float units; keep 16B alignment for frag buffers)
    float* f = (float*)d_ws;
    float* spec = f;                                    // 16384
    unsigned short* afrag_hi = (unsigned short*)(f + 16384);   // 16384 bf16 = 8192 f
    unsigned short* afrag_lo = (unsigned short*)(f + 16384 + 8192);
    float* m_part = f + 16384 + 16384;                  // 128*NB1 ([o][b])
    float* l_part = m_part + (size_t)128 * NB1;
    float* scale = l_part + (size_t)128 * NB1;          // 128*NB1
    float* partial2 = scale + (size_t)128 * NB1;        // 8*16384
    float* partialsA = partial2 + 8 * 16384;

    size_t fixed_bytes = ((size_t)(16384 * 2) + (size_t)NB1 * 128 * 3 + (size_t)8 * 16384) * 4;
    int nA = 512;
    if (ws_size > fixed_bytes) {
        size_t avail = (ws_size - fixed_bytes) / 65536;   // 64KB per partial
        if ((size_t)nA > avail) nA = (int)avail;
    } else {
        nA = 1;
    }
    if (nA < 1) nA = 1;
    int chunk = (N_PTS + nA - 1) / nA;

    kA<<<nA, 512, 0, stream>>>(U, x, partialsA, chunk);
    kA2a<<<512, 256, 0, stream>>>(partialsA, partial2, nA);
    kA2b<<<64, 256, 0, stream>>>(partial2, spec);
    kB<<<4096, 256, 0, stream>>>(coeffs, spec, afrag_hi, afrag_lo);
    kC1<<<NB1, 512, 0, stream>>>(U, afrag_hi, afrag_lo, out, m_part, l_part);
    kC2<<<128, 256, 0, stream>>>(m_part, l_part, scale);
    kC3<<<NB1, 256, 0, stream>>>(out, scale);
}